// Round 1
// baseline (766.399 us; speedup 1.0000x reference)
//
#include <hip/hip_runtime.h>
#include <hip/hip_bf16.h>
#include <math.h>

typedef short short8 __attribute__((ext_vector_type(8)));
typedef float f32x4 __attribute__((ext_vector_type(4)));

#define DEV static __device__ __forceinline__

DEV void gl2lds16(const void* g, void* l) {
  __builtin_amdgcn_global_load_lds(
      (const __attribute__((address_space(1))) unsigned int*)g,
      (__attribute__((address_space(3))) unsigned int*)l, 16, 0, 0);
}

DEV float wred_sum(float v) {
#pragma unroll
  for (int o = 1; o < 64; o <<= 1) v += __shfl_xor(v, o, 64);
  return v;
}
DEV float wred_max(float v) {
#pragma unroll
  for (int o = 1; o < 64; o <<= 1) v = fmaxf(v, __shfl_xor(v, o, 64));
  return v;
}
DEV float sigmoidf(float x) { return 1.0f / (1.0f + expf(-x)); }

// fp32 -> bf16 RNE (cold path)
DEV unsigned short f2bf(float x) {
  unsigned u = __float_as_uint(x);
  unsigned rr = (u + 0x7fffu + ((u >> 16) & 1u)) >> 16;
  return (unsigned short)rr;
}

// hot-path packed convert: 8 fp32 -> 8 bf16 via v_cvt_pk_bf16_f32
DEV short8 cvt8(float4 f0, float4 f1) {
  union { short8 s; unsigned u[4]; } r;
  asm("v_cvt_pk_bf16_f32 %0, %1, %2" : "=v"(r.u[0]) : "v"(f0.x), "v"(f0.y));
  asm("v_cvt_pk_bf16_f32 %0, %1, %2" : "=v"(r.u[1]) : "v"(f0.z), "v"(f0.w));
  asm("v_cvt_pk_bf16_f32 %0, %1, %2" : "=v"(r.u[2]) : "v"(f1.x), "v"(f1.y));
  asm("v_cvt_pk_bf16_f32 %0, %1, %2" : "=v"(r.u[3]) : "v"(f1.z), "v"(f1.w));
  return r.s;
}

// output layout (floats): out[50257] | h1[1024] | c1[1024] | weighted[1024] | psel[32]
#define OUT_H1 50257
#define OUT_C1 51281
#define OUT_W  52305
#define OUT_PS 53329

// ---------------- P0: transpose+convert Wa_bot (rows 1024..2047) -> WaT[n][k] bf16
__global__ void k_prep_bT(const float* __restrict__ Wa, unsigned short* __restrict__ WaT) {
  __shared__ float tile[64][65];
  int bi = blockIdx.x, bj = blockIdx.y, t = threadIdx.x;
  int c = t & 63, rq = t >> 6;
#pragma unroll
  for (int rr = 0; rr < 16; rr++) {
    int kl = rr * 4 + rq;
    tile[kl][c] = Wa[(size_t)(1024 + bi * 64 + kl) * 1024 + bj * 64 + c];
  }
  __syncthreads();
#pragma unroll
  for (int rr = 0; rr < 16; rr++) {
    int nl = rr * 4 + rq;
    WaT[(size_t)(bj * 64 + nl) * 1024 + bi * 64 + c] = f2bf(tile[c][nl]);
  }
}

// ---------------- K1: hWa = h0@Wa_top + ba ; hWh = h0@Wh + bh ; embed gather ; nz sums
__global__ void k_prep_small(const float* __restrict__ Wa, const float* __restrict__ ba,
                             const float* __restrict__ Wh, const float* __restrict__ bh,
                             const float* __restrict__ hid, const float* __restrict__ embed,
                             const int* __restrict__ idx, const float* __restrict__ pmat,
                             float* __restrict__ hWa, float* __restrict__ hWh,
                             float* __restrict__ yinp, float* __restrict__ nz) {
  __shared__ float red[4][64];
  __shared__ float r2[4];
  int bx = blockIdx.x, t = threadIdx.x;
  if (bx < 32) {
    int ol = t & 63, kc = t >> 6;
    int o = bx * 64 + ol;
    const float* W = (o < 1024) ? Wa : Wh;
    int col = (o < 1024) ? o : (o - 1024);
    float acc = 0.f;
    for (int k = kc * 256; k < kc * 256 + 256; k++) acc += hid[k] * W[(size_t)k * 1024 + col];
    red[kc][ol] = acc;
    __syncthreads();
    if (t < 64) {
      int oo = bx * 64 + t;
      float s = red[0][t] + red[1][t] + red[2][t] + red[3][t];
      if (oo < 1024) hWa[oo] = s + ba[oo];
      else hWh[oo - 1024] = s + bh[oo - 1024];
    }
  } else if (bx == 32) {
    int id = idx[0];
    for (int k = t; k < 300; k += 256) yinp[k] = embed[(size_t)id * 300 + k];
  } else {
    int j = bx - 33;
    float a = 0.f;
    for (int k = t; k < 32768; k += 256) a += pmat[(size_t)j * 32768 + k];
    a = wred_sum(a);
    if ((t & 63) == 0) r2[t >> 6] = a;
    __syncthreads();
    if (t == 0) nz[j] = r2[0] + r2[1] + r2[2] + r2[3];
  }
}

// ---------------- K2: scores GEMM. E = enc@Wa_bot ; part[ntile][row] = sum_n va*tanh(E+hWa)
__global__ __launch_bounds__(256) void k_scores_gemm(
    const float* __restrict__ ex, const float* __restrict__ ec,
    const unsigned short* __restrict__ WaT, const float* __restrict__ hWa,
    const float* __restrict__ va, float* __restrict__ scoresP) {
  __shared__ __align__(16) float As[128 * 32];          // [row][k] fp32
  __shared__ __align__(16) unsigned short Bs[128 * 32]; // [n][k] bf16
  __shared__ float red[2][128];
  int mtile = blockIdx.x, ntile = blockIdx.y;
  int t = threadIdx.x, lane = t & 63, wid = t >> 6;
  int wr = wid >> 1, wc = wid & 1;
  int l15 = lane & 15, lg = lane >> 4;
  int r0 = mtile * 128;
  const float* Asrc = (r0 < 8192) ? (ex + (size_t)r0 * 1024) : (ec + (size_t)(r0 - 8192) * 1024);

  f32x4 acc[4][4];
#pragma unroll
  for (int m = 0; m < 4; m++)
#pragma unroll
    for (int n = 0; n < 4; n++) acc[m][n] = (f32x4){0.f, 0.f, 0.f, 0.f};

  for (int kt = 0; kt < 1024; kt += 32) {
    // stage A: 128x32 fp32 = 1024 16B-chunks, 4 passes; chunk c: row=c>>3, k0=(c&7)*4
#pragma unroll
    for (int p = 0; p < 4; p++) {
      int cb = p * 256 + wid * 64;
      int c = cb + lane;
      const float* g = Asrc + (size_t)(c >> 3) * 1024 + kt + (c & 7) * 4;
      gl2lds16(g, &As[cb * 4]);
    }
    // stage B: 128x32 bf16 = 512 16B-chunks, 2 passes; chunk c: n=c>>2, k0=(c&3)*8
#pragma unroll
    for (int p = 0; p < 2; p++) {
      int cb = p * 256 + wid * 64;
      int c = cb + lane;
      const unsigned short* g = WaT + (size_t)(ntile * 128 + (c >> 2)) * 1024 + kt + (c & 3) * 8;
      gl2lds16(g, &Bs[cb * 8]);
    }
    __syncthreads();
    short8 a[4], b[4];
#pragma unroll
    for (int m = 0; m < 4; m++) {
      const float* ap = &As[(wr * 64 + m * 16 + l15) * 32 + lg * 8];
      float4 f0 = *(const float4*)ap;
      float4 f1 = *(const float4*)(ap + 4);
      a[m] = cvt8(f0, f1);
    }
#pragma unroll
    for (int n = 0; n < 4; n++)
      b[n] = *(const short8*)&Bs[(wc * 64 + n * 16 + l15) * 32 + lg * 8];
#pragma unroll
    for (int m = 0; m < 4; m++)
#pragma unroll
      for (int n = 0; n < 4; n++)
        acc[m][n] = __builtin_amdgcn_mfma_f32_16x16x32_bf16(a[m], b[n], acc[m][n], 0, 0, 0);
    __syncthreads();
  }

  // epilogue: D frag layout col=lane&15, row=4*(lane>>4)+j  [verified m89]
  float vva[4], hba[4];
#pragma unroll
  for (int n = 0; n < 4; n++) {
    int col = ntile * 128 + wc * 64 + n * 16 + l15;
    vva[n] = va[col];
    hba[n] = hWa[col];
  }
#pragma unroll
  for (int m = 0; m < 4; m++) {
#pragma unroll
    for (int j = 0; j < 4; j++) {
      float p = 0.f;
#pragma unroll
      for (int n = 0; n < 4; n++) p += vva[n] * tanhf(acc[m][n][j] + hba[n]);
#pragma unroll
      for (int o = 1; o < 16; o <<= 1) p += __shfl_xor(p, o, 64);
      if (l15 == 0) red[wc][wr * 64 + m * 16 + lg * 4 + j] = p;
    }
  }
  __syncthreads();
  if (t < 128) scoresP[(size_t)ntile * 12288 + r0 + t] = red[0][t] + red[1][t];
}

// ---------------- K2b: scores[r] = sum over 8 ntiles
__global__ void k_scores_reduce(const float* __restrict__ scoresP, float* __restrict__ scores) {
  int r = blockIdx.x * 256 + threadIdx.x;
  float s = 0.f;
#pragma unroll
  for (int nt = 0; nt < 8; nt++) s += scoresP[(size_t)nt * 12288 + r];
  scores[r] = s;
}

// ---------------- K3a: softmax stats (max, sumexp) per segment
__global__ void k_softmax_stats(const float* __restrict__ scores, float* __restrict__ sstat) {
  __shared__ float rbuf[4];
  int t = threadIdx.x;
  for (int seg = 0; seg < 2; seg++) {
    int base = seg ? 8192 : 0, len = seg ? 4096 : 8192;
    float m = -1e30f;
    for (int r = t; r < len; r += 256) m = fmaxf(m, scores[base + r]);
    m = wred_max(m);
    if ((t & 63) == 0) rbuf[t >> 6] = m;
    __syncthreads();
    m = fmaxf(fmaxf(rbuf[0], rbuf[1]), fmaxf(rbuf[2], rbuf[3]));
    __syncthreads();
    float z = 0.f;
    for (int r = t; r < len; r += 256) z += expf(scores[base + r] - m);
    z = wred_sum(z);
    if ((t & 63) == 0) rbuf[t >> 6] = z;
    __syncthreads();
    if (t == 0) { sstat[seg * 2] = m; sstat[seg * 2 + 1] = rbuf[0] + rbuf[1] + rbuf[2] + rbuf[3]; }
    __syncthreads();
  }
}

// ---------------- K3b: weighted-sum partials over 256-row chunks
__global__ void k_weighted_part(const float* __restrict__ ex, const float* __restrict__ ec,
                                const float* __restrict__ scores, const float* __restrict__ sstat,
                                float* __restrict__ partw) {
  int b = blockIdx.x, t = threadIdx.x;
  int seg = (b < 32) ? 0 : 1;
  int rb = seg ? (b - 32) * 256 : b * 256;
  const float* src = seg ? ec : ex;
  int sbase = seg ? 8192 : 0;
  float m = sstat[seg * 2], invz = 1.0f / sstat[seg * 2 + 1];
  float a0 = 0.f, a1 = 0.f, a2 = 0.f, a3 = 0.f;
  for (int r = 0; r < 256; r++) {
    float w = expf(scores[sbase + rb + r] - m) * invz;
    const float* row = src + (size_t)(rb + r) * 1024;
    a0 += w * row[t]; a1 += w * row[t + 256]; a2 += w * row[t + 512]; a3 += w * row[t + 768];
  }
  float* dst = partw + (size_t)b * 1024;
  dst[t] = a0; dst[t + 256] = a1; dst[t + 512] = a2; dst[t + 768] = a3;
}

// ---------------- K3c: combine -> wxc[0:1024]=weighted_x, [1024:2048]=weighted_c
__global__ void k_weighted_combine(const float* __restrict__ partw, float* __restrict__ wxc) {
  int t = threadIdx.x;
  for (int q = 0; q < 4; q++) {
    int d = t + q * 256;
    float sx = 0.f, sc = 0.f;
    for (int b = 0; b < 32; b++) sx += partw[(size_t)b * 1024 + d];
    for (int b = 32; b < 48; b++) sc += partw[(size_t)b * 1024 + d];
    wxc[d] = sx; wxc[1024 + d] = sc;
  }
}

// ---------------- K4: weighted = wxc @ Wg + bg  (also output slot 3)
__global__ void k_weighted_gemv(const float* __restrict__ wxc, const float* __restrict__ Wg,
                                const float* __restrict__ bg, float* __restrict__ weighted,
                                float* __restrict__ dout) {
  __shared__ float red[4][64];
  int bx = blockIdx.x, t = threadIdx.x;
  int ol = t & 63, kc = t >> 6;
  int o = bx * 64 + ol;
  float acc = 0.f;
  for (int k = kc * 512; k < kc * 512 + 512; k++) acc += wxc[k] * Wg[(size_t)k * 1024 + o];
  red[kc][ol] = acc;
  __syncthreads();
  if (t < 64) {
    int oo = bx * 64 + t;
    float v = red[0][t] + red[1][t] + red[2][t] + red[3][t] + bg[oo];
    weighted[oo] = v;
    dout[OUT_W + oo] = v;
  }
}

// ---------------- K5: char gate logits -> sel = argmax(softmax(l)*nz)  (monotone -> masked argmax)
__global__ void k_char_sel(const float* __restrict__ yinp, const float* __restrict__ hid,
                           const float* __restrict__ weighted, const float* __restrict__ Wchar,
                           const float* __restrict__ bchar, const float* __restrict__ nz,
                           int* __restrict__ sel) {
  __shared__ float XL[2348];
  __shared__ float red[4][6];
  int t = threadIdx.x;
  for (int k = t; k < 2348; k += 256)
    XL[k] = (k < 300) ? yinp[k] : (k < 1324 ? hid[k - 300] : weighted[k - 1324]);
  __syncthreads();
  float p[6] = {0.f, 0.f, 0.f, 0.f, 0.f, 0.f};
  for (int k = t; k < 2348; k += 256) {
    float xv = XL[k];
#pragma unroll
    for (int ch = 0; ch < 6; ch++) p[ch] += xv * Wchar[k * 6 + ch];
  }
#pragma unroll
  for (int ch = 0; ch < 6; ch++) {
    float v = wred_sum(p[ch]);
    if ((t & 63) == 0) red[t >> 6][ch] = v;
  }
  __syncthreads();
  if (t == 0) {
    float best = -1e30f; int si = 0;
    for (int ch = 0; ch < 6; ch++) {
      float lgt = red[0][ch] + red[1][ch] + red[2][ch] + red[3][ch] + bchar[ch];
      if (nz[ch] != 0.0f && lgt > best) { best = lgt; si = ch; }
    }
    *sel = si;
  }
}

// ---------------- K6a: pp[i] = p_matrix[sel*32+i] @ Wp + bp for i in 0..31
__global__ void k_pp(const float* __restrict__ pmat, const float* __restrict__ Wp,
                     const float* __restrict__ bp, const int* __restrict__ sel,
                     float* __restrict__ pp) {
  __shared__ float srow[1024];
  int i = blockIdx.x >> 2, oq = blockIdx.x & 3;
  int t = threadIdx.x;
  int row = (*sel) * 32 + i;
  for (int k = t; k < 1024; k += 256) srow[k] = pmat[(size_t)row * 1024 + k];
  __syncthreads();
  int o = oq * 256 + t;
  float acc = 0.f;
#pragma unroll 4
  for (int k = 0; k < 1024; k++) acc += srow[k] * Wp[(size_t)k * 1024 + o];
  pp[i * 1024 + o] = acc + bp[o];
}

// ---------------- K6b: att(33 dots) -> softmax over 192 -> psel out + p_attn
__global__ void k_pattn(const float* __restrict__ pmat, const float* __restrict__ pp,
                        const float* __restrict__ hWh, const float* __restrict__ bp,
                        const float* __restrict__ vv, const int* __restrict__ sel,
                        float* __restrict__ pattn, float* __restrict__ dout) {
  __shared__ float att[33]; // 0..31 real rows, 32 = att_zero
  __shared__ float r4[4];
  __shared__ float sc32[32];
  int t = threadIdx.x, lane = t & 63, w = t >> 6;
  for (int i = 0; i <= 32; i++) {
    float pt = 0.f;
    if (i < 32) {
      for (int n = t; n < 1024; n += 256) pt += vv[n] * tanhf(hWh[n] + pp[i * 1024 + n]);
    } else {
      for (int n = t; n < 1024; n += 256) pt += vv[n] * tanhf(hWh[n] + bp[n]);
    }
    pt = wred_sum(pt);
    if (lane == 0) r4[w] = pt;
    __syncthreads();
    if (t == 0) att[i] = r4[0] + r4[1] + r4[2] + r4[3];
    __syncthreads();
  }
  if (t == 0) {
    float m = att[32];
    for (int i = 0; i < 32; i++) m = fmaxf(m, att[i]);
    float Z = 160.0f * expf(att[32] - m);
    for (int i = 0; i < 32; i++) Z += expf(att[i] - m);
    for (int i = 0; i < 32; i++) sc32[i] = expf(att[i] - m) / Z;
  }
  __syncthreads();
  if (t < 32) dout[OUT_PS + t] = sc32[t];
  int srow0 = (*sel) * 32;
  for (int q = 0; q < 4; q++) {
    int d = t + q * 256;
    float acc = 0.f;
#pragma unroll
    for (int i = 0; i < 32; i++) acc += sc32[i] * pmat[(size_t)(srow0 + i) * 1024 + d];
    pattn[d] = acc;
  }
}

// ---------------- K7a: y_in = concat(y_input, weighted, p_attn) @ Wy + by
__global__ void k_yin(const float* __restrict__ yinp, const float* __restrict__ weighted,
                      const float* __restrict__ pattn, const float* __restrict__ Wy,
                      const float* __restrict__ by, float* __restrict__ yin) {
  __shared__ float XL[2348];
  __shared__ float red[4][64];
  int bx = blockIdx.x, t = threadIdx.x;
  for (int k = t; k < 2348; k += 256)
    XL[k] = (k < 300) ? yinp[k] : (k < 1324 ? weighted[k - 300] : pattn[k - 1324]);
  __syncthreads();
  int ol = t & 63, kc = t >> 6;
  int o = bx * 64 + ol;
  float acc = 0.f;
  if (o < 300) {
    int k0 = kc * 587, k1 = k0 + 587; if (k1 > 2348) k1 = 2348;
    for (int k = k0; k < k1; k++) acc += XL[k] * Wy[(size_t)k * 300 + o];
  }
  red[kc][ol] = acc;
  __syncthreads();
  if (t < 64) {
    int oo = bx * 64 + t;
    if (oo < 300) yin[oo] = red[0][t] + red[1][t] + red[2][t] + red[3][t] + by[oo];
  }
}

// ---------------- K7b: gates = y_in@Wih + h0@Whh + bih + bhh
__global__ void k_gates(const float* __restrict__ yin, const float* __restrict__ hid,
                        const float* __restrict__ Wih, const float* __restrict__ Whh,
                        const float* __restrict__ bih, const float* __restrict__ bhh,
                        float* __restrict__ gates) {
  __shared__ float YL[300];
  __shared__ float red[4][64];
  int bx = blockIdx.x, t = threadIdx.x;
  for (int k = t; k < 300; k += 256) YL[k] = yin[k];
  __syncthreads();
  int ol = t & 63, kc = t >> 6;
  int o = bx * 64 + ol;
  float acc = 0.f;
  {
    int k0 = kc * 75, k1 = k0 + 75;
    for (int k = k0; k < k1; k++) acc += YL[k] * Wih[(size_t)k * 4096 + o];
  }
  {
    int k0 = kc * 256;
    for (int k = k0; k < k0 + 256; k++) acc += hid[k] * Whh[(size_t)k * 4096 + o];
  }
  red[kc][ol] = acc;
  __syncthreads();
  if (t < 64) {
    int oo = bx * 64 + t;
    gates[oo] = red[0][t] + red[1][t] + red[2][t] + red[3][t] + bih[oo] + bhh[oo];
  }
}

// ---------------- K7c: LSTM pointwise -> h1, c1 (outputs 1,2)
__global__ void k_lstm(const float* __restrict__ gates, const float* __restrict__ c0,
                       float* __restrict__ h1ws, float* __restrict__ dout) {
  int t = threadIdx.x;
  for (int q = 0; q < 4; q++) {
    int d = t + q * 256;
    float gi = gates[d], gf = gates[1024 + d], gg = gates[2048 + d], go = gates[3072 + d];
    float c1 = sigmoidf(gf) * c0[d] + sigmoidf(gi) * tanhf(gg);
    float h1 = sigmoidf(go) * tanhf(c1);
    h1ws[d] = h1;
    dout[OUT_H1 + d] = h1;
    dout[OUT_C1 + d] = c1;
  }
}

// ---------------- K8: logits partials = h1 @ Wout, k-split 16
__global__ __launch_bounds__(256) void k_out_gemv(const float* __restrict__ h1,
                                                  const float* __restrict__ Wout,
                                                  float* __restrict__ partK) {
  __shared__ float hh[64];
  int ks = blockIdx.x, cb = blockIdx.y, t = threadIdx.x;
  if (t < 64) hh[t] = h1[ks * 64 + t];
  __syncthreads();
  int c0 = cb * 1024 + t;
  float a0 = 0.f, a1 = 0.f, a2 = 0.f, a3 = 0.f;
  const float* W = Wout + (size_t)ks * 64 * 50257;
#pragma unroll 4
  for (int k = 0; k < 64; k++) {
    const float* row = W + (size_t)k * 50257;
    float h = hh[k];
    if (c0 < 50257)       a0 += h * row[c0];
    if (c0 + 256 < 50257) a1 += h * row[c0 + 256];
    if (c0 + 512 < 50257) a2 += h * row[c0 + 512];
    if (c0 + 768 < 50257) a3 += h * row[c0 + 768];
  }
  float* dst = partK + (size_t)ks * 50257;
  if (c0 < 50257)       dst[c0] = a0;
  if (c0 + 256 < 50257) dst[c0 + 256] = a1;
  if (c0 + 512 < 50257) dst[c0 + 512] = a2;
  if (c0 + 768 < 50257) dst[c0 + 768] = a3;
}

// ---------------- K9a: logits = sum partials + bout ; per-block max & sumexp
__global__ void k_logits_stats(const float* __restrict__ partK, const float* __restrict__ bout,
                               float* __restrict__ logits, float* __restrict__ bstat) {
  __shared__ float r4[4];
  int cb = blockIdx.x, t = threadIdx.x;
  float l[4];
  float m = -1e30f;
  for (int q = 0; q < 4; q++) {
    int c = cb * 1024 + t + q * 256;
    float v = -1e30f;
    if (c < 50257) {
      v = bout[c];
#pragma unroll
      for (int ks = 0; ks < 16; ks++) v += partK[(size_t)ks * 50257 + c];
      logits[c] = v;
    }
    l[q] = v;
    m = fmaxf(m, v);
  }
  m = wred_max(m);
  if ((t & 63) == 0) r4[t >> 6] = m;
  __syncthreads();
  m = fmaxf(fmaxf(r4[0], r4[1]), fmaxf(r4[2], r4[3]));
  __syncthreads();
  float z = 0.f;
  for (int q = 0; q < 4; q++) {
    int c = cb * 1024 + t + q * 256;
    if (c < 50257) z += expf(l[q] - m);
  }
  z = wred_sum(z);
  if ((t & 63) == 0) r4[t >> 6] = z;
  __syncthreads();
  if (t == 0) { bstat[cb] = m; bstat[64 + cb] = r4[0] + r4[1] + r4[2] + r4[3]; }
}

// ---------------- K9b: global softmax stats
__global__ void k_gstats(const float* __restrict__ bstat, float* __restrict__ stat2) {
  if (threadIdx.x == 0) {
    float M = -1e30f;
    for (int b = 0; b < 50; b++) M = fmaxf(M, bstat[b]);
    float Z = 0.f;
    for (int b = 0; b < 50; b++) Z += bstat[64 + b] * expf(bstat[b] - M);
    stat2[0] = M; stat2[1] = Z;
  }
}

// ---------------- K9c: out = exp(logit - M)/Z
__global__ void k_out_final(const float* __restrict__ logits, const float* __restrict__ stat2,
                            float* __restrict__ dout) {
  int c = blockIdx.x * 1024 + threadIdx.x;
  float M = stat2[0], Z = stat2[1];
  for (int q = 0; q < 4; q++) {
    int cc = c + q * 256;
    if (cc < 50257) dout[cc] = expf(logits[cc] - M) / Z;
  }
}

extern "C" void kernel_launch(void* const* d_in, const int* in_sizes, int n_in,
                              void* d_out, int out_size, void* d_ws, size_t ws_size,
                              hipStream_t stream) {
  (void)in_sizes; (void)n_in; (void)out_size; (void)ws_size;
  const int*   idx   = (const int*)  d_in[0];
  const float* ex    = (const float*)d_in[1];
  const float* ec    = (const float*)d_in[2];
  const float* pmat  = (const float*)d_in[3];
  const float* hid   = (const float*)d_in[4];
  const float* c0    = (const float*)d_in[5];
  const float* embed = (const float*)d_in[8];
  const float* Wa    = (const float*)d_in[9];
  const float* ba    = (const float*)d_in[10];
  const float* va    = (const float*)d_in[11];
  const float* Wg    = (const float*)d_in[12];
  const float* bg    = (const float*)d_in[13];
  const float* Wchar = (const float*)d_in[14];
  const float* bchar = (const float*)d_in[15];
  const float* Wp    = (const float*)d_in[16];
  const float* bp    = (const float*)d_in[17];
  const float* Wh    = (const float*)d_in[18];
  const float* bh    = (const float*)d_in[19];
  const float* vv    = (const float*)d_in[20];
  const float* Wy    = (const float*)d_in[21];
  const float* by    = (const float*)d_in[22];
  const float* Wih   = (const float*)d_in[23];
  const float* Whh   = (const float*)d_in[24];
  const float* bih   = (const float*)d_in[25];
  const float* bhh   = (const float*)d_in[26];
  const float* Wout  = (const float*)d_in[27];
  const float* bout  = (const float*)d_in[28];
  float* out = (float*)d_out;

  char* ws = (char*)d_ws;
  unsigned short* WaT = (unsigned short*)(ws + 0);          // 2,097,152 B
  float* scoresP  = (float*)(ws + 2097152);                 //   393,216
  float* scores   = (float*)(ws + 2490368);                 //    49,152
  float* sstat    = (float*)(ws + 2539520);                 //       256
  float* hWa      = (float*)(ws + 2539776);                 //     4,096
  float* hWh      = (float*)(ws + 2543872);                 //     4,096
  float* yinp     = (float*)(ws + 2547968);                 //     1,280
  float* nz       = (float*)(ws + 2549248);                 //       256
  float* partw    = (float*)(ws + 2549504);                 //   196,608
  float* wxc      = (float*)(ws + 2746112);                 //     8,192
  float* weighted = (float*)(ws + 2754304);                 //     4,096
  int*   sel      = (int*)  (ws + 2758400);                 //       256
  float* pp       = (float*)(ws + 2758656);                 //   131,072
  float* pattn    = (float*)(ws + 2889728);                 //     4,096
  float* yin      = (float*)(ws + 2893824);                 //     1,280
  float* gates    = (float*)(ws + 2895104);                 //    16,384
  float* h1       = (float*)(ws + 2911488);                 //     4,096
  float* partK    = (float*)(ws + 2915584);                 // 3,216,448
  float* logits   = (float*)(ws + 6132032);                 //   201,152
  float* bstat    = (float*)(ws + 6333184);                 //       512
  float* stat2    = (float*)(ws + 6333696);                 //        64

  k_prep_bT<<<dim3(16, 16), 256, 0, stream>>>(Wa, WaT);
  k_prep_small<<<39, 256, 0, stream>>>(Wa, ba, Wh, bh, hid, embed, idx, pmat, hWa, hWh, yinp, nz);
  k_scores_gemm<<<dim3(96, 8), 256, 0, stream>>>(ex, ec, WaT, hWa, va, scoresP);
  k_scores_reduce<<<48, 256, 0, stream>>>(scoresP, scores);
  k_softmax_stats<<<1, 256, 0, stream>>>(scores, sstat);
  k_weighted_part<<<48, 256, 0, stream>>>(ex, ec, scores, sstat, partw);
  k_weighted_combine<<<1, 256, 0, stream>>>(partw, wxc);
  k_weighted_gemv<<<16, 256, 0, stream>>>(wxc, Wg, bg, weighted, out);
  k_char_sel<<<1, 256, 0, stream>>>(yinp, hid, weighted, Wchar, bchar, nz, sel);
  k_pp<<<128, 256, 0, stream>>>(pmat, Wp, bp, sel, pp);
  k_pattn<<<1, 256, 0, stream>>>(pmat, pp, hWh, bp, vv, sel, pattn, out);
  k_yin<<<5, 256, 0, stream>>>(yinp, weighted, pattn, Wy, by, yin);
  k_gates<<<64, 256, 0, stream>>>(yin, hid, Wih, Whh, bih, bhh, gates);
  k_lstm<<<1, 256, 0, stream>>>(gates, c0, h1, out);
  k_out_gemv<<<dim3(16, 50), 256, 0, stream>>>(h1, Wout, partK);
  k_logits_stats<<<50, 256, 0, stream>>>(partK, bout, logits, bstat);
  k_gstats<<<1, 64, 0, stream>>>(bstat, stat2);
  k_out_final<<<50, 256, 0, stream>>>(logits, stat2, out);
}

// Round 2
// 430.613 us; speedup vs baseline: 1.7798x; 1.7798x over previous
//
#include <hip/hip_runtime.h>
#include <hip/hip_bf16.h>
#include <math.h>

typedef short short8 __attribute__((ext_vector_type(8)));
typedef float f32x4 __attribute__((ext_vector_type(4)));

#define DEV static __device__ __forceinline__

DEV void gl2lds16(const void* g, void* l) {
  __builtin_amdgcn_global_load_lds(
      (const __attribute__((address_space(1))) unsigned int*)g,
      (__attribute__((address_space(3))) unsigned int*)l, 16, 0, 0);
}

DEV float wred_sum(float v) {
#pragma unroll
  for (int o = 1; o < 64; o <<= 1) v += __shfl_xor(v, o, 64);
  return v;
}
DEV float wred_max(float v) {
#pragma unroll
  for (int o = 1; o < 64; o <<= 1) v = fmaxf(v, __shfl_xor(v, o, 64));
  return v;
}
DEV float sigmoidf(float x) { return 1.0f / (1.0f + expf(-x)); }

DEV unsigned short f2bf(float x) {
  unsigned u = __float_as_uint(x);
  unsigned rr = (u + 0x7fffu + ((u >> 16) & 1u)) >> 16;
  return (unsigned short)rr;
}

DEV short8 cvt8(float4 f0, float4 f1) {
  union { short8 s; unsigned u[4]; } r;
  asm("v_cvt_pk_bf16_f32 %0, %1, %2" : "=v"(r.u[0]) : "v"(f0.x), "v"(f0.y));
  asm("v_cvt_pk_bf16_f32 %0, %1, %2" : "=v"(r.u[1]) : "v"(f0.z), "v"(f0.w));
  asm("v_cvt_pk_bf16_f32 %0, %1, %2" : "=v"(r.u[2]) : "v"(f1.x), "v"(f1.y));
  asm("v_cvt_pk_bf16_f32 %0, %1, %2" : "=v"(r.u[3]) : "v"(f1.z), "v"(f1.w));
  return r.s;
}

// output layout (floats): out[50257] | h1[1024] | c1[1024] | weighted[1024] | psel[32]
#define OUT_H1 50257
#define OUT_C1 51281
#define OUT_W  52305
#define OUT_PS 53329

// ---------------- P0: transpose+convert Wa_bot (rows 1024..2047) -> WaT[n][k] bf16
__global__ void k_prep_bT(const float* __restrict__ Wa, unsigned short* __restrict__ WaT) {
  __shared__ float tile[64][65];
  int bi = blockIdx.x, bj = blockIdx.y, t = threadIdx.x;
  int c = t & 63, rq = t >> 6;
#pragma unroll
  for (int rr = 0; rr < 16; rr++) {
    int kl = rr * 4 + rq;
    tile[kl][c] = Wa[(size_t)(1024 + bi * 64 + kl) * 1024 + bj * 64 + c];
  }
  __syncthreads();
#pragma unroll
  for (int rr = 0; rr < 16; rr++) {
    int nl = rr * 4 + rq;
    WaT[(size_t)(bj * 64 + nl) * 1024 + bi * 64 + c] = f2bf(tile[c][nl]);
  }
}

// ---------------- K1: hWa = h0@Wa_top + ba ; hWh = h0@Wh + bh ; embed gather ; nz sums
__global__ void k_prep_small(const float* __restrict__ Wa, const float* __restrict__ ba,
                             const float* __restrict__ Wh, const float* __restrict__ bh,
                             const float* __restrict__ hid, const float* __restrict__ embed,
                             const int* __restrict__ idx, const float* __restrict__ pmat,
                             float* __restrict__ hWa, float* __restrict__ hWh,
                             float* __restrict__ yinp, float* __restrict__ nz) {
  __shared__ float red[4][64];
  __shared__ float r2[4];
  int bx = blockIdx.x, t = threadIdx.x;
  if (bx < 32) {
    int ol = t & 63, kc = t >> 6;
    int o = bx * 64 + ol;
    const float* W = (o < 1024) ? Wa : Wh;
    int col = (o < 1024) ? o : (o - 1024);
    float acc = 0.f;
    for (int k = kc * 256; k < kc * 256 + 256; k++) acc += hid[k] * W[(size_t)k * 1024 + col];
    red[kc][ol] = acc;
    __syncthreads();
    if (t < 64) {
      int oo = bx * 64 + t;
      float s = red[0][t] + red[1][t] + red[2][t] + red[3][t];
      if (oo < 1024) hWa[oo] = s + ba[oo];
      else hWh[oo - 1024] = s + bh[oo - 1024];
    }
  } else if (bx == 32) {
    int id = idx[0];
    for (int k = t; k < 300; k += 256) yinp[k] = embed[(size_t)id * 300 + k];
  } else {
    int j = bx - 33;
    float a = 0.f;
    for (int k = t; k < 32768; k += 256) a += pmat[(size_t)j * 32768 + k];
    a = wred_sum(a);
    if ((t & 63) == 0) r2[t >> 6] = a;
    __syncthreads();
    if (t == 0) nz[j] = r2[0] + r2[1] + r2[2] + r2[3];
  }
}

// ---------------- K2: scores GEMM. E = enc@Wa_bot ; part[ntile][row] = sum_n va*tanh(E+hWa)
__global__ __launch_bounds__(256) void k_scores_gemm(
    const float* __restrict__ ex, const float* __restrict__ ec,
    const unsigned short* __restrict__ WaT, const float* __restrict__ hWa,
    const float* __restrict__ va, float* __restrict__ scoresP) {
  __shared__ __align__(16) float As[128 * 32];          // [row][k] fp32
  __shared__ __align__(16) unsigned short Bs[128 * 32]; // [n][k] bf16
  __shared__ float red[2][128];
  int mtile = blockIdx.x, ntile = blockIdx.y;
  int t = threadIdx.x, lane = t & 63, wid = t >> 6;
  int wr = wid >> 1, wc = wid & 1;
  int l15 = lane & 15, lg = lane >> 4;
  int r0 = mtile * 128;
  const float* Asrc = (r0 < 8192) ? (ex + (size_t)r0 * 1024) : (ec + (size_t)(r0 - 8192) * 1024);

  f32x4 acc[4][4];
#pragma unroll
  for (int m = 0; m < 4; m++)
#pragma unroll
    for (int n = 0; n < 4; n++) acc[m][n] = (f32x4){0.f, 0.f, 0.f, 0.f};

  for (int kt = 0; kt < 1024; kt += 32) {
#pragma unroll
    for (int p = 0; p < 4; p++) {
      int cb = p * 256 + wid * 64;
      int c = cb + lane;
      const float* g = Asrc + (size_t)(c >> 3) * 1024 + kt + (c & 7) * 4;
      gl2lds16(g, &As[cb * 4]);
    }
#pragma unroll
    for (int p = 0; p < 2; p++) {
      int cb = p * 256 + wid * 64;
      int c = cb + lane;
      const unsigned short* g = WaT + (size_t)(ntile * 128 + (c >> 2)) * 1024 + kt + (c & 3) * 8;
      gl2lds16(g, &Bs[cb * 8]);
    }
    __syncthreads();
    short8 a[4], b[4];
#pragma unroll
    for (int m = 0; m < 4; m++) {
      const float* ap = &As[(wr * 64 + m * 16 + l15) * 32 + lg * 8];
      float4 f0 = *(const float4*)ap;
      float4 f1 = *(const float4*)(ap + 4);
      a[m] = cvt8(f0, f1);
    }
#pragma unroll
    for (int n = 0; n < 4; n++)
      b[n] = *(const short8*)&Bs[(wc * 64 + n * 16 + l15) * 32 + lg * 8];
#pragma unroll
    for (int m = 0; m < 4; m++)
#pragma unroll
      for (int n = 0; n < 4; n++)
        acc[m][n] = __builtin_amdgcn_mfma_f32_16x16x32_bf16(a[m], b[n], acc[m][n], 0, 0, 0);
    __syncthreads();
  }

  float vva[4], hba[4];
#pragma unroll
  for (int n = 0; n < 4; n++) {
    int col = ntile * 128 + wc * 64 + n * 16 + l15;
    vva[n] = va[col];
    hba[n] = hWa[col];
  }
#pragma unroll
  for (int m = 0; m < 4; m++) {
#pragma unroll
    for (int j = 0; j < 4; j++) {
      float p = 0.f;
#pragma unroll
      for (int n = 0; n < 4; n++) p += vva[n] * tanhf(acc[m][n][j] + hba[n]);
#pragma unroll
      for (int o = 1; o < 16; o <<= 1) p += __shfl_xor(p, o, 64);
      if (l15 == 0) red[wc][wr * 64 + m * 16 + lg * 4 + j] = p;
    }
  }
  __syncthreads();
  if (t < 128) scoresP[(size_t)ntile * 12288 + r0 + t] = red[0][t] + red[1][t];
}

// ---------------- K2b: scores[r] = sum over 8 ntiles ; fused per-block softmax stats
__global__ void k_scores_reduce(const float* __restrict__ scoresP, float* __restrict__ scores,
                                float* __restrict__ bmax, float* __restrict__ bz) {
  __shared__ float r4[4];
  int bx = blockIdx.x, t = threadIdx.x;
  int r = bx * 256 + t;
  float s = 0.f;
#pragma unroll
  for (int nt = 0; nt < 8; nt++) s += scoresP[(size_t)nt * 12288 + r];
  scores[r] = s;
  float m = wred_max(s);
  if ((t & 63) == 0) r4[t >> 6] = m;
  __syncthreads();
  m = fmaxf(fmaxf(r4[0], r4[1]), fmaxf(r4[2], r4[3]));
  __syncthreads();
  float z = expf(s - m);
  z = wred_sum(z);
  if ((t & 63) == 0) r4[t >> 6] = z;
  __syncthreads();
  if (t == 0) { bmax[bx] = m; bz[bx] = r4[0] + r4[1] + r4[2] + r4[3]; }
}

// ---------------- K2c: merge block stats per segment (seg0: blocks 0..31, seg1: 32..47)
__global__ void k_sstat(const float* __restrict__ bmax, const float* __restrict__ bz,
                        float* __restrict__ sstat) {
  int t = threadIdx.x;
  if (t < 2) {
    int b0 = t ? 32 : 0, b1 = t ? 48 : 32;
    float M = -1e30f;
    for (int b = b0; b < b1; b++) M = fmaxf(M, bmax[b]);
    float Z = 0.f;
    for (int b = b0; b < b1; b++) Z += bz[b] * expf(bmax[b] - M);
    sstat[t * 2] = M; sstat[t * 2 + 1] = Z;
  }
}

// ---------------- K3b: weighted-sum partials over 64-row chunks (x:128 blocks, c:64)
__global__ void k_weighted_part(const float* __restrict__ ex, const float* __restrict__ ec,
                                const float* __restrict__ scores, const float* __restrict__ sstat,
                                float* __restrict__ partw) {
  int b = blockIdx.x, t = threadIdx.x;
  int seg = (b >= 128) ? 1 : 0;
  int rb = seg ? (b - 128) * 64 : b * 64;
  const float* src = seg ? ec : ex;
  int sbase = seg ? 8192 : 0;
  float m = sstat[seg * 2], invz = 1.0f / sstat[seg * 2 + 1];
  float a0 = 0.f, a1 = 0.f, a2 = 0.f, a3 = 0.f;
#pragma unroll 4
  for (int r = 0; r < 64; r++) {
    float w = expf(scores[sbase + rb + r] - m) * invz;
    const float* row = src + (size_t)(rb + r) * 1024;
    a0 += w * row[t]; a1 += w * row[t + 256]; a2 += w * row[t + 512]; a3 += w * row[t + 768];
  }
  float* dst = partw + (size_t)b * 1024;
  dst[t] = a0; dst[t + 256] = a1; dst[t + 512] = a2; dst[t + 768] = a3;
}

// ---------------- K3c: combine -> wxc[0:1024]=weighted_x, [1024:2048]=weighted_c
__global__ void k_weighted_combine(const float* __restrict__ partw, float* __restrict__ wxc) {
  int d = blockIdx.x * 256 + threadIdx.x;
  float sx = 0.f, sc = 0.f;
#pragma unroll 8
  for (int b = 0; b < 128; b++) sx += partw[(size_t)b * 1024 + d];
#pragma unroll 8
  for (int b = 128; b < 192; b++) sc += partw[(size_t)b * 1024 + d];
  wxc[d] = sx; wxc[1024 + d] = sc;
}

// ---------------- K4: weighted partials = wxc @ Wg, k-split 32
__global__ void k_weighted_gemv(const float* __restrict__ wxc, const float* __restrict__ Wg,
                                float* __restrict__ wgP) {
  int o = blockIdx.x * 256 + threadIdx.x;
  int kb = blockIdx.y * 64;
  float acc = 0.f;
#pragma unroll 8
  for (int k = kb; k < kb + 64; k++) acc += wxc[k] * Wg[(size_t)k * 1024 + o];
  wgP[(size_t)blockIdx.y * 1024 + o] = acc;
}

// ---------------- K4b: weighted = sum partials + bg (also output slot 3)
__global__ void k_wg_fin(const float* __restrict__ wgP, const float* __restrict__ bg,
                         float* __restrict__ weighted, float* __restrict__ dout) {
  int t = threadIdx.x;
  for (int q = 0; q < 4; q++) {
    int d = t + q * 256;
    float s = bg[d];
#pragma unroll 8
    for (int b = 0; b < 32; b++) s += wgP[(size_t)b * 1024 + d];
    weighted[d] = s;
    dout[OUT_W + d] = s;
  }
}

// ---------------- K5: char gate logits -> sel = argmax(softmax(l)*nz)
__global__ void k_char_sel(const float* __restrict__ yinp, const float* __restrict__ hid,
                           const float* __restrict__ weighted, const float* __restrict__ Wchar,
                           const float* __restrict__ bchar, const float* __restrict__ nz,
                           int* __restrict__ sel) {
  __shared__ float XL[2348];
  __shared__ float red[4][6];
  int t = threadIdx.x;
  for (int k = t; k < 2348; k += 256)
    XL[k] = (k < 300) ? yinp[k] : (k < 1324 ? hid[k - 300] : weighted[k - 1324]);
  __syncthreads();
  float p[6] = {0.f, 0.f, 0.f, 0.f, 0.f, 0.f};
  for (int k = t; k < 2348; k += 256) {
    float xv = XL[k];
#pragma unroll
    for (int ch = 0; ch < 6; ch++) p[ch] += xv * Wchar[k * 6 + ch];
  }
#pragma unroll
  for (int ch = 0; ch < 6; ch++) {
    float v = wred_sum(p[ch]);
    if ((t & 63) == 0) red[t >> 6][ch] = v;
  }
  __syncthreads();
  if (t == 0) {
    float best = -1e30f; int si = 0;
    for (int ch = 0; ch < 6; ch++) {
      float lgt = red[0][ch] + red[1][ch] + red[2][ch] + red[3][ch] + bchar[ch];
      if (nz[ch] != 0.0f && lgt > best) { best = lgt; si = ch; }
    }
    *sel = si;
  }
}

// ---------------- K6a: pp[i] = p_matrix[sel*32+i] @ Wp + bp for i in 0..31
__global__ void k_pp(const float* __restrict__ pmat, const float* __restrict__ Wp,
                     const float* __restrict__ bp, const int* __restrict__ sel,
                     float* __restrict__ pp) {
  __shared__ float srow[1024];
  int i = blockIdx.x >> 2, oq = blockIdx.x & 3;
  int t = threadIdx.x;
  int row = (*sel) * 32 + i;
  for (int k = t; k < 1024; k += 256) srow[k] = pmat[(size_t)row * 1024 + k];
  __syncthreads();
  int o = oq * 256 + t;
  float acc = 0.f;
#pragma unroll 4
  for (int k = 0; k < 1024; k++) acc += srow[k] * Wp[(size_t)k * 1024 + o];
  pp[i * 1024 + o] = acc + bp[o];
}

// ---------------- K6b: att[i] dot products (i = 0..31 rows, 32 = att_zero)
__global__ void k_att(const float* __restrict__ pp, const float* __restrict__ hWh,
                      const float* __restrict__ bp, const float* __restrict__ vv,
                      float* __restrict__ attb) {
  __shared__ float r4[4];
  int i = blockIdx.x, t = threadIdx.x;
  const float* src = (i < 32) ? (pp + i * 1024) : bp;
  float pt = 0.f;
  for (int n = t; n < 1024; n += 256) pt += vv[n] * tanhf(hWh[n] + src[n]);
  pt = wred_sum(pt);
  if ((t & 63) == 0) r4[t >> 6] = pt;
  __syncthreads();
  if (t == 0) attb[i] = r4[0] + r4[1] + r4[2] + r4[3];
}

// ---------------- K6c: softmax over 192 (160 zero-slots share att_zero) -> psel + p_attn
__global__ void k_pattn2(const float* __restrict__ attb, const float* __restrict__ pmat,
                         const int* __restrict__ sel, float* __restrict__ pattn,
                         float* __restrict__ dout) {
  __shared__ float sc32[32];
  int t = threadIdx.x, bx = blockIdx.x;
  if (t == 0) {
    float az = attb[32];
    float m = az;
    for (int i = 0; i < 32; i++) m = fmaxf(m, attb[i]);
    float Z = 160.0f * expf(az - m);
    for (int i = 0; i < 32; i++) Z += expf(attb[i] - m);
    for (int i = 0; i < 32; i++) sc32[i] = expf(attb[i] - m) / Z;
  }
  __syncthreads();
  if (bx == 0 && t < 32) dout[OUT_PS + t] = sc32[t];
  int d = bx * 256 + t;
  int srow0 = (*sel) * 32;
  float acc = 0.f;
#pragma unroll
  for (int i = 0; i < 32; i++) acc += sc32[i] * pmat[(size_t)(srow0 + i) * 1024 + d];
  pattn[d] = acc;
}

// ---------------- K7a: y_in partials: k-split 32, coalesced over 300 outputs
__global__ void k_yin_part(const float* __restrict__ yinp, const float* __restrict__ weighted,
                           const float* __restrict__ pattn, const float* __restrict__ Wy,
                           float* __restrict__ yinP) {
  __shared__ float XLb[74];
  int b = blockIdx.x, t = threadIdx.x;
  int base = b * 74;
  int len = 2348 - base; if (len > 74) len = 74;
  if (t < len) {
    int k = base + t;
    XLb[t] = (k < 300) ? yinp[k] : (k < 1324 ? weighted[k - 300] : pattn[k - 1324]);
  }
  __syncthreads();
  if (t < 300) {
    float acc = 0.f;
    for (int j = 0; j < len; j++) acc += XLb[j] * Wy[(size_t)(base + j) * 300 + t];
    yinP[b * 300 + t] = acc;
  }
}

// ---------------- K7b: gates = y_in@Wih + h0@Whh + bih + bhh (y_in reduced from partials)
__global__ void k_gates(const float* __restrict__ yinP, const float* __restrict__ by,
                        const float* __restrict__ hid,
                        const float* __restrict__ Wih, const float* __restrict__ Whh,
                        const float* __restrict__ bih, const float* __restrict__ bhh,
                        float* __restrict__ gates) {
  __shared__ float YL[300];
  __shared__ float red[4][64];
  int bx = blockIdx.x, t = threadIdx.x;
  for (int k = t; k < 300; k += 256) {
    float s = by[k];
#pragma unroll 8
    for (int b = 0; b < 32; b++) s += yinP[b * 300 + k];
    YL[k] = s;
  }
  __syncthreads();
  int ol = t & 63, kc = t >> 6;
  int o = bx * 64 + ol;
  float acc = 0.f;
  {
    int k0 = kc * 75, k1 = k0 + 75;
    for (int k = k0; k < k1; k++) acc += YL[k] * Wih[(size_t)k * 4096 + o];
  }
  {
    int k0 = kc * 256;
    for (int k = k0; k < k0 + 256; k++) acc += hid[k] * Whh[(size_t)k * 4096 + o];
  }
  red[kc][ol] = acc;
  __syncthreads();
  if (t < 64) {
    int oo = bx * 64 + t;
    gates[oo] = red[0][t] + red[1][t] + red[2][t] + red[3][t] + bih[oo] + bhh[oo];
  }
}

// ---------------- K7c: LSTM pointwise -> h1, c1 (outputs 1,2)
__global__ void k_lstm(const float* __restrict__ gates, const float* __restrict__ c0,
                       float* __restrict__ h1ws, float* __restrict__ dout) {
  int t = threadIdx.x;
  for (int q = 0; q < 4; q++) {
    int d = t + q * 256;
    float gi = gates[d], gf = gates[1024 + d], gg = gates[2048 + d], go = gates[3072 + d];
    float c1 = sigmoidf(gf) * c0[d] + sigmoidf(gi) * tanhf(gg);
    float h1 = sigmoidf(go) * tanhf(c1);
    h1ws[d] = h1;
    dout[OUT_H1 + d] = h1;
    dout[OUT_C1 + d] = c1;
  }
}

// ---------------- K8: logits partials = h1 @ Wout, k-split 16
__global__ __launch_bounds__(256) void k_out_gemv(const float* __restrict__ h1,
                                                  const float* __restrict__ Wout,
                                                  float* __restrict__ partK) {
  __shared__ float hh[64];
  int ks = blockIdx.x, cb = blockIdx.y, t = threadIdx.x;
  if (t < 64) hh[t] = h1[ks * 64 + t];
  __syncthreads();
  int c0 = cb * 1024 + t;
  float a0 = 0.f, a1 = 0.f, a2 = 0.f, a3 = 0.f;
  const float* W = Wout + (size_t)ks * 64 * 50257;
#pragma unroll 4
  for (int k = 0; k < 64; k++) {
    const float* row = W + (size_t)k * 50257;
    float h = hh[k];
    if (c0 < 50257)       a0 += h * row[c0];
    if (c0 + 256 < 50257) a1 += h * row[c0 + 256];
    if (c0 + 512 < 50257) a2 += h * row[c0 + 512];
    if (c0 + 768 < 50257) a3 += h * row[c0 + 768];
  }
  float* dst = partK + (size_t)ks * 50257;
  if (c0 < 50257)       dst[c0] = a0;
  if (c0 + 256 < 50257) dst[c0 + 256] = a1;
  if (c0 + 512 < 50257) dst[c0 + 512] = a2;
  if (c0 + 768 < 50257) dst[c0 + 768] = a3;
}

// ---------------- K9a: logits = sum partials + bout ; per-block max & sumexp
__global__ void k_logits_stats(const float* __restrict__ partK, const float* __restrict__ bout,
                               float* __restrict__ logits, float* __restrict__ bstat) {
  __shared__ float r4[4];
  int cb = blockIdx.x, t = threadIdx.x;
  float l[4];
  float m = -1e30f;
  for (int q = 0; q < 4; q++) {
    int c = cb * 1024 + t + q * 256;
    float v = -1e30f;
    if (c < 50257) {
      v = bout[c];
#pragma unroll
      for (int ks = 0; ks < 16; ks++) v += partK[(size_t)ks * 50257 + c];
      logits[c] = v;
    }
    l[q] = v;
    m = fmaxf(m, v);
  }
  m = wred_max(m);
  if ((t & 63) == 0) r4[t >> 6] = m;
  __syncthreads();
  m = fmaxf(fmaxf(r4[0], r4[1]), fmaxf(r4[2], r4[3]));
  __syncthreads();
  float z = 0.f;
  for (int q = 0; q < 4; q++) {
    int c = cb * 1024 + t + q * 256;
    if (c < 50257) z += expf(l[q] - m);
  }
  z = wred_sum(z);
  if ((t & 63) == 0) r4[t >> 6] = z;
  __syncthreads();
  if (t == 0) { bstat[cb] = m; bstat[64 + cb] = r4[0] + r4[1] + r4[2] + r4[3]; }
}

// ---------------- K9b: global softmax stats
__global__ void k_gstats(const float* __restrict__ bstat, float* __restrict__ stat2) {
  if (threadIdx.x == 0) {
    float M = -1e30f;
    for (int b = 0; b < 50; b++) M = fmaxf(M, bstat[b]);
    float Z = 0.f;
    for (int b = 0; b < 50; b++) Z += bstat[64 + b] * expf(bstat[b] - M);
    stat2[0] = M; stat2[1] = Z;
  }
}

// ---------------- K9c: out = exp(logit - M)/Z
__global__ void k_out_final(const float* __restrict__ logits, const float* __restrict__ stat2,
                            float* __restrict__ dout) {
  int c = blockIdx.x * 1024 + threadIdx.x;
  float M = stat2[0], Z = stat2[1];
  for (int q = 0; q < 4; q++) {
    int cc = c + q * 256;
    if (cc < 50257) dout[cc] = expf(logits[cc] - M) / Z;
  }
}

extern "C" void kernel_launch(void* const* d_in, const int* in_sizes, int n_in,
                              void* d_out, int out_size, void* d_ws, size_t ws_size,
                              hipStream_t stream) {
  (void)in_sizes; (void)n_in; (void)out_size; (void)ws_size;
  const int*   idx   = (const int*)  d_in[0];
  const float* ex    = (const float*)d_in[1];
  const float* ec    = (const float*)d_in[2];
  const float* pmat  = (const float*)d_in[3];
  const float* hid   = (const float*)d_in[4];
  const float* c0    = (const float*)d_in[5];
  const float* embed = (const float*)d_in[8];
  const float* Wa    = (const float*)d_in[9];
  const float* ba    = (const float*)d_in[10];
  const float* va    = (const float*)d_in[11];
  const float* Wg    = (const float*)d_in[12];
  const float* bg    = (const float*)d_in[13];
  const float* Wchar = (const float*)d_in[14];
  const float* bchar = (const float*)d_in[15];
  const float* Wp    = (const float*)d_in[16];
  const float* bp    = (const float*)d_in[17];
  const float* Wh    = (const float*)d_in[18];
  const float* bh    = (const float*)d_in[19];
  const float* vv    = (const float*)d_in[20];
  const float* Wy    = (const float*)d_in[21];
  const float* by    = (const float*)d_in[22];
  const float* Wih   = (const float*)d_in[23];
  const float* Whh   = (const float*)d_in[24];
  const float* bih   = (const float*)d_in[25];
  const float* bhh   = (const float*)d_in[26];
  const float* Wout  = (const float*)d_in[27];
  const float* bout  = (const float*)d_in[28];
  float* out = (float*)d_out;

  char* ws = (char*)d_ws;
  // Zone A (time-multiplexed):
  //  phase 1: WaT | scoresP | scores | bmax | bz | partw | wxc | wgP
  //  phase 2 (all phase-1 dead before k_out_gemv): partK | logits
  unsigned short* WaT = (unsigned short*)(ws + 0);          // 2,097,152
  float* scoresP  = (float*)(ws + 2097152);                 //   393,216
  float* scores   = (float*)(ws + 2490368);                 //    49,152
  float* bmax     = (float*)(ws + 2539520);                 //       256
  float* bz       = (float*)(ws + 2539776);                 //       256
  float* partw    = (float*)(ws + 2540032);                 //   786,432
  float* wxc      = (float*)(ws + 3326464);                 //     8,192
  float* wgP      = (float*)(ws + 3334656);                 //   131,072 (ends 3,465,728)
  float* partK    = (float*)(ws + 0);                       // 3,216,448
  float* logits   = (float*)(ws + 3216640);                 //   201,152 (ends 3,417,792)
  // Zone B (persistent), base 3,465,728
  float* sstat    = (float*)(ws + 3465728);                 //       256
  float* hWa      = (float*)(ws + 3465984);                 //     4,096
  float* hWh      = (float*)(ws + 3470080);                 //     4,096
  float* yinp     = (float*)(ws + 3474176);                 //     1,536
  float* nz       = (float*)(ws + 3475712);                 //       256
  float* weighted = (float*)(ws + 3475968);                 //     4,096
  int*   sel      = (int*)  (ws + 3480064);                 //       256
  float* pp       = (float*)(ws + 3480320);                 //   131,072
  float* pattn    = (float*)(ws + 3611392);                 //     4,096
  float* attb     = (float*)(ws + 3615488);                 //       256
  float* yinP     = (float*)(ws + 3615744);                 //    38,656
  float* gates    = (float*)(ws + 3654400);                 //    16,384
  float* h1       = (float*)(ws + 3670784);                 //     4,096
  float* bstat    = (float*)(ws + 3674880);                 //       512
  float* stat2    = (float*)(ws + 3675392);                 //        64

  k_prep_bT<<<dim3(16, 16), 256, 0, stream>>>(Wa, WaT);
  k_prep_small<<<39, 256, 0, stream>>>(Wa, ba, Wh, bh, hid, embed, idx, pmat, hWa, hWh, yinp, nz);
  k_scores_gemm<<<dim3(96, 8), 256, 0, stream>>>(ex, ec, WaT, hWa, va, scoresP);
  k_scores_reduce<<<48, 256, 0, stream>>>(scoresP, scores, bmax, bz);
  k_sstat<<<1, 64, 0, stream>>>(bmax, bz, sstat);
  k_weighted_part<<<192, 256, 0, stream>>>(ex, ec, scores, sstat, partw);
  k_weighted_combine<<<4, 256, 0, stream>>>(partw, wxc);
  k_weighted_gemv<<<dim3(4, 32), 256, 0, stream>>>(wxc, Wg, wgP);
  k_wg_fin<<<1, 256, 0, stream>>>(wgP, bg, weighted, out);
  k_char_sel<<<1, 256, 0, stream>>>(yinp, hid, weighted, Wchar, bchar, nz, sel);
  k_pp<<<128, 256, 0, stream>>>(pmat, Wp, bp, sel, pp);
  k_att<<<33, 256, 0, stream>>>(pp, hWh, bp, vv, attb);
  k_pattn2<<<4, 256, 0, stream>>>(attb, pmat, sel, pattn, out);
  k_yin_part<<<32, 320, 0, stream>>>(yinp, weighted, pattn, Wy, yinP);
  k_gates<<<64, 256, 0, stream>>>(yinP, by, hid, Wih, Whh, bih, bhh, gates);
  k_lstm<<<1, 256, 0, stream>>>(gates, c0, h1, out);
  k_out_gemv<<<dim3(16, 50), 256, 0, stream>>>(h1, Wout, partK);
  k_logits_stats<<<50, 256, 0, stream>>>(partK, bout, logits, bstat);
  k_gstats<<<1, 64, 0, stream>>>(bstat, stat2);
  k_out_final<<<50, 256, 0, stream>>>(logits, stat2, out);
}

// Round 3
// 272.917 us; speedup vs baseline: 2.8082x; 1.5778x over previous
//
#include <hip/hip_runtime.h>
#include <hip/hip_bf16.h>
#include <math.h>

typedef short short8 __attribute__((ext_vector_type(8)));
typedef float f32x4 __attribute__((ext_vector_type(4)));

#define DEV static __device__ __forceinline__

DEV void gl2lds16(const void* g, void* l) {
  __builtin_amdgcn_global_load_lds(
      (const __attribute__((address_space(1))) unsigned int*)g,
      (__attribute__((address_space(3))) unsigned int*)l, 16, 0, 0);
}

DEV float wred_sum(float v) {
#pragma unroll
  for (int o = 1; o < 64; o <<= 1) v += __shfl_xor(v, o, 64);
  return v;
}
DEV float wred_max(float v) {
#pragma unroll
  for (int o = 1; o < 64; o <<= 1) v = fmaxf(v, __shfl_xor(v, o, 64));
  return v;
}
DEV float sigmoidf(float x) { return 1.0f / (1.0f + expf(-x)); }

DEV unsigned short f2bf(float x) {
  unsigned u = __float_as_uint(x);
  unsigned rr = (u + 0x7fffu + ((u >> 16) & 1u)) >> 16;
  return (unsigned short)rr;
}

DEV short8 cvt8(float4 f0, float4 f1) {
  union { short8 s; unsigned u[4]; } r;
  asm("v_cvt_pk_bf16_f32 %0, %1, %2" : "=v"(r.u[0]) : "v"(f0.x), "v"(f0.y));
  asm("v_cvt_pk_bf16_f32 %0, %1, %2" : "=v"(r.u[1]) : "v"(f0.z), "v"(f0.w));
  asm("v_cvt_pk_bf16_f32 %0, %1, %2" : "=v"(r.u[2]) : "v"(f1.x), "v"(f1.y));
  asm("v_cvt_pk_bf16_f32 %0, %1, %2" : "=v"(r.u[3]) : "v"(f1.z), "v"(f1.w));
  return r.s;
}

// output layout (floats): out[50257] | h1[1024] | c1[1024] | weighted[1024] | psel[32]
#define OUT_H1 50257
#define OUT_C1 51281
#define OUT_W  52305
#define OUT_PS 53329

// ---------------- P0: transpose+convert Wa_bot (rows 1024..2047) -> WaT[n][k] bf16
__global__ void k_prep_bT(const float* __restrict__ Wa, unsigned short* __restrict__ WaT) {
  __shared__ float tile[64][65];
  int bi = blockIdx.x, bj = blockIdx.y, t = threadIdx.x;
  int c = t & 63, rq = t >> 6;
#pragma unroll
  for (int rr = 0; rr < 16; rr++) {
    int kl = rr * 4 + rq;
    tile[kl][c] = Wa[(size_t)(1024 + bi * 64 + kl) * 1024 + bj * 64 + c];
  }
  __syncthreads();
#pragma unroll
  for (int rr = 0; rr < 16; rr++) {
    int nl = rr * 4 + rq;
    WaT[(size_t)(bj * 64 + nl) * 1024 + bi * 64 + c] = f2bf(tile[c][nl]);
  }
}

// ---------------- K1: hWa = h0@Wa_top + ba ; hWh = h0@Wh + bh ; embed gather ; nz sums (512 thr)
__global__ void k_prep_small(const float* __restrict__ Wa, const float* __restrict__ ba,
                             const float* __restrict__ Wh, const float* __restrict__ bh,
                             const float* __restrict__ hid, const float* __restrict__ embed,
                             const int* __restrict__ idx, const float* __restrict__ pmat,
                             float* __restrict__ hWa, float* __restrict__ hWh,
                             float* __restrict__ yinp, float* __restrict__ nz) {
  __shared__ float red[8][64];
  __shared__ float r2[8];
  int bx = blockIdx.x, t = threadIdx.x;
  if (bx < 32) {
    int ol = t & 63, kc = t >> 6;  // kc 0..7
    int o = bx * 64 + ol;
    const float* W = (o < 1024) ? Wa : Wh;
    int col = (o < 1024) ? o : (o - 1024);
    float acc = 0.f;
#pragma unroll 4
    for (int k = kc * 128; k < kc * 128 + 128; k++) acc += hid[k] * W[(size_t)k * 1024 + col];
    red[kc][ol] = acc;
    __syncthreads();
    if (t < 64) {
      int oo = bx * 64 + t;
      float s = 0.f;
#pragma unroll
      for (int q = 0; q < 8; q++) s += red[q][t];
      if (oo < 1024) hWa[oo] = s + ba[oo];
      else hWh[oo - 1024] = s + bh[oo - 1024];
    }
  } else if (bx == 32) {
    int id = idx[0];
    for (int k = t; k < 300; k += 512) yinp[k] = embed[(size_t)id * 300 + k];
  } else {
    int j = bx - 33;
    float a = 0.f;
    for (int k = t; k < 32768; k += 512) a += pmat[(size_t)j * 32768 + k];
    a = wred_sum(a);
    if ((t & 63) == 0) r2[t >> 6] = a;
    __syncthreads();
    if (t == 0) {
      float s = 0.f;
#pragma unroll
      for (int q = 0; q < 8; q++) s += r2[q];
      nz[j] = s;
    }
  }
}

// ---------------- K2: scores GEMM. E = enc@Wa_bot ; part[ntile][row] = sum_n va*tanh(E+hWa)
__global__ __launch_bounds__(256) void k_scores_gemm(
    const float* __restrict__ ex, const float* __restrict__ ec,
    const unsigned short* __restrict__ WaT, const float* __restrict__ hWa,
    const float* __restrict__ va, float* __restrict__ scoresP) {
  __shared__ __align__(16) float As[128 * 32];
  __shared__ __align__(16) unsigned short Bs[128 * 32];
  __shared__ float red[2][128];
  int mtile = blockIdx.x, ntile = blockIdx.y;
  int t = threadIdx.x, lane = t & 63, wid = t >> 6;
  int wr = wid >> 1, wc = wid & 1;
  int l15 = lane & 15, lg = lane >> 4;
  int r0 = mtile * 128;
  const float* Asrc = (r0 < 8192) ? (ex + (size_t)r0 * 1024) : (ec + (size_t)(r0 - 8192) * 1024);

  f32x4 acc[4][4];
#pragma unroll
  for (int m = 0; m < 4; m++)
#pragma unroll
    for (int n = 0; n < 4; n++) acc[m][n] = (f32x4){0.f, 0.f, 0.f, 0.f};

  for (int kt = 0; kt < 1024; kt += 32) {
#pragma unroll
    for (int p = 0; p < 4; p++) {
      int cb = p * 256 + wid * 64;
      int c = cb + lane;
      const float* g = Asrc + (size_t)(c >> 3) * 1024 + kt + (c & 7) * 4;
      gl2lds16(g, &As[cb * 4]);
    }
#pragma unroll
    for (int p = 0; p < 2; p++) {
      int cb = p * 256 + wid * 64;
      int c = cb + lane;
      const unsigned short* g = WaT + (size_t)(ntile * 128 + (c >> 2)) * 1024 + kt + (c & 3) * 8;
      gl2lds16(g, &Bs[cb * 8]);
    }
    __syncthreads();
    short8 a[4], b[4];
#pragma unroll
    for (int m = 0; m < 4; m++) {
      const float* ap = &As[(wr * 64 + m * 16 + l15) * 32 + lg * 8];
      float4 f0 = *(const float4*)ap;
      float4 f1 = *(const float4*)(ap + 4);
      a[m] = cvt8(f0, f1);
    }
#pragma unroll
    for (int n = 0; n < 4; n++)
      b[n] = *(const short8*)&Bs[(wc * 64 + n * 16 + l15) * 32 + lg * 8];
#pragma unroll
    for (int m = 0; m < 4; m++)
#pragma unroll
      for (int n = 0; n < 4; n++)
        acc[m][n] = __builtin_amdgcn_mfma_f32_16x16x32_bf16(a[m], b[n], acc[m][n], 0, 0, 0);
    __syncthreads();
  }

  float vva[4], hba[4];
#pragma unroll
  for (int n = 0; n < 4; n++) {
    int col = ntile * 128 + wc * 64 + n * 16 + l15;
    vva[n] = va[col];
    hba[n] = hWa[col];
  }
#pragma unroll
  for (int m = 0; m < 4; m++) {
#pragma unroll
    for (int j = 0; j < 4; j++) {
      float p = 0.f;
#pragma unroll
      for (int n = 0; n < 4; n++) p += vva[n] * tanhf(acc[m][n][j] + hba[n]);
#pragma unroll
      for (int o = 1; o < 16; o <<= 1) p += __shfl_xor(p, o, 64);
      if (l15 == 0) red[wc][wr * 64 + m * 16 + lg * 4 + j] = p;
    }
  }
  __syncthreads();
  if (t < 128) scoresP[(size_t)ntile * 12288 + r0 + t] = red[0][t] + red[1][t];
}

// ---------------- K2b: scores[r] = sum over 8 ntiles ; fused per-block softmax stats
__global__ void k_scores_reduce(const float* __restrict__ scoresP, float* __restrict__ scores,
                                float* __restrict__ bmax, float* __restrict__ bz) {
  __shared__ float r4[4];
  int bx = blockIdx.x, t = threadIdx.x;
  int r = bx * 256 + t;
  float s = 0.f;
#pragma unroll
  for (int nt = 0; nt < 8; nt++) s += scoresP[(size_t)nt * 12288 + r];
  scores[r] = s;
  float m = wred_max(s);
  if ((t & 63) == 0) r4[t >> 6] = m;
  __syncthreads();
  m = fmaxf(fmaxf(r4[0], r4[1]), fmaxf(r4[2], r4[3]));
  __syncthreads();
  float z = expf(s - m);
  z = wred_sum(z);
  if ((t & 63) == 0) r4[t >> 6] = z;
  __syncthreads();
  if (t == 0) { bmax[bx] = m; bz[bx] = r4[0] + r4[1] + r4[2] + r4[3]; }
}

// ---------------- K3: weighted-sum partials, 64-row x 256-col tiles; stat merge folded in
__global__ void k_weighted_part(const float* __restrict__ ex, const float* __restrict__ ec,
                                const float* __restrict__ scores, const float* __restrict__ bmax,
                                const float* __restrict__ bz, float* __restrict__ partw) {
  __shared__ float wrow[64];
  int b = blockIdx.x, colq = blockIdx.y, t = threadIdx.x;
  int seg = (b >= 128) ? 1 : 0;
  int rb = (seg ? (b - 128) : b) * 64;
  int sbase = seg ? 8192 : 0;
  if (t < 64) {
    int b0 = seg ? 32 : 0, cnt = seg ? 16 : 32;
    float mv = (t < cnt) ? bmax[b0 + t] : -1e30f;
    float m = wred_max(mv);
    float zv = (t < cnt) ? bz[b0 + t] * expf(bmax[b0 + t] - m) : 0.f;
    float z = wred_sum(zv);
    wrow[t] = expf(scores[sbase + rb + t] - m) / z;
  }
  __syncthreads();
  const float* src = seg ? ec : ex;
  int col = colq * 256 + t;
  float acc = 0.f;
#pragma unroll 8
  for (int r = 0; r < 64; r++) acc += wrow[r] * src[(size_t)(rb + r) * 1024 + col];
  partw[(size_t)b * 1024 + col] = acc;
}

// ---------------- K3c: combine -> wxc[0:1024]=weighted_x, [1024:2048]=weighted_c
__global__ void k_weighted_combine(const float* __restrict__ partw, float* __restrict__ wxc) {
  int d = blockIdx.x * 256 + threadIdx.x;
  float sx = 0.f, sc = 0.f;
#pragma unroll 8
  for (int b = 0; b < 128; b++) sx += partw[(size_t)b * 1024 + d];
#pragma unroll 8
  for (int b = 128; b < 192; b++) sc += partw[(size_t)b * 1024 + d];
  wxc[d] = sx; wxc[1024 + d] = sc;
}

// ---------------- K4: weighted partials = wxc @ Wg, k-split 32
__global__ void k_weighted_gemv(const float* __restrict__ wxc, const float* __restrict__ Wg,
                                float* __restrict__ wgP) {
  int o = blockIdx.x * 256 + threadIdx.x;
  int kb = blockIdx.y * 64;
  float acc = 0.f;
#pragma unroll 8
  for (int k = kb; k < kb + 64; k++) acc += wxc[k] * Wg[(size_t)k * 1024 + o];
  wgP[(size_t)blockIdx.y * 1024 + o] = acc;
}

// ---------------- K4b+K5 merged: weighted = sum partials + bg ; char gate argmax -> sel
__global__ void k_wgfin_charsel(const float* __restrict__ wgP, const float* __restrict__ bg,
                                const float* __restrict__ yinp, const float* __restrict__ hid,
                                const float* __restrict__ Wchar, const float* __restrict__ bchar,
                                const float* __restrict__ nz, float* __restrict__ weighted,
                                int* __restrict__ sel, float* __restrict__ dout) {
  __shared__ float WL[1024];
  __shared__ float red[4][6];
  int t = threadIdx.x;
  for (int q = 0; q < 4; q++) {
    int d = t + q * 256;
    float s = bg[d];
#pragma unroll 8
    for (int b = 0; b < 32; b++) s += wgP[(size_t)b * 1024 + d];
    WL[d] = s;
    weighted[d] = s;
    dout[OUT_W + d] = s;
  }
  __syncthreads();
  float p[6] = {0.f, 0.f, 0.f, 0.f, 0.f, 0.f};
  for (int k = t; k < 2348; k += 256) {
    float xv = (k < 300) ? yinp[k] : (k < 1324 ? hid[k - 300] : WL[k - 1324]);
#pragma unroll
    for (int ch = 0; ch < 6; ch++) p[ch] += xv * Wchar[k * 6 + ch];
  }
#pragma unroll
  for (int ch = 0; ch < 6; ch++) {
    float v = wred_sum(p[ch]);
    if ((t & 63) == 0) red[t >> 6][ch] = v;
  }
  __syncthreads();
  if (t == 0) {
    float best = -1e30f; int si = 0;
    for (int ch = 0; ch < 6; ch++) {
      float lgt = red[0][ch] + red[1][ch] + red[2][ch] + red[3][ch] + bchar[ch];
      if (nz[ch] != 0.0f && lgt > best) { best = lgt; si = ch; }
    }
    *sel = si;
  }
}

// ---------------- K6a: ppP[kq][i][o] partials; Wp element read once, applied to all 32 rows
__global__ void k_pp(const float* __restrict__ pmat, const float* __restrict__ Wp,
                     const int* __restrict__ sel, float* __restrict__ ppP) {
  __shared__ float sr[32][64];  // 8 KB
  int oq = blockIdx.x, kq = blockIdx.y, t = threadIdx.x;
  int row0 = (*sel) * 32;
  int k0 = kq * 64;
#pragma unroll
  for (int j = 0; j < 8; j++) {
    int idx = t + j * 256;
    int i = idx >> 6, kk = idx & 63;
    sr[i][kk] = pmat[(size_t)(row0 + i) * 1024 + k0 + kk];
  }
  __syncthreads();
  int o = oq * 256 + t;
  float acc[32];
#pragma unroll
  for (int i = 0; i < 32; i++) acc[i] = 0.f;
  for (int k = 0; k < 64; k++) {
    float w = Wp[(size_t)(k0 + k) * 1024 + o];
#pragma unroll
    for (int i = 0; i < 32; i++) acc[i] += sr[i][k] * w;
  }
#pragma unroll
  for (int i = 0; i < 32; i++) ppP[(size_t)kq * 32768 + i * 1024 + o] = acc[i];
}

// ---------------- K6a2: pp[i][o] = sum_kq ppP + bp
__global__ void k_pp_fin(const float* __restrict__ ppP, const float* __restrict__ bp,
                         float* __restrict__ pp) {
  int i = blockIdx.x, t = threadIdx.x;
  for (int q = 0; q < 4; q++) {
    int d = t + q * 256;
    float s = bp[d];
#pragma unroll
    for (int kq = 0; kq < 16; kq++) s += ppP[(size_t)kq * 32768 + i * 1024 + d];
    pp[i * 1024 + d] = s;
  }
}

// ---------------- K6b: att[i] dot products (i = 0..31 rows, 32 = att_zero)
__global__ void k_att(const float* __restrict__ pp, const float* __restrict__ hWh,
                      const float* __restrict__ bp, const float* __restrict__ vv,
                      float* __restrict__ attb) {
  __shared__ float r4[4];
  int i = blockIdx.x, t = threadIdx.x;
  const float* src = (i < 32) ? (pp + i * 1024) : bp;
  float pt = 0.f;
  for (int n = t; n < 1024; n += 256) pt += vv[n] * tanhf(hWh[n] + src[n]);
  pt = wred_sum(pt);
  if ((t & 63) == 0) r4[t >> 6] = pt;
  __syncthreads();
  if (t == 0) attb[i] = r4[0] + r4[1] + r4[2] + r4[3];
}

// ---------------- K6c: softmax over 192 (160 zero-slots share att_zero) -> psel + p_attn
__global__ void k_pattn2(const float* __restrict__ attb, const float* __restrict__ pmat,
                         const int* __restrict__ sel, float* __restrict__ pattn,
                         float* __restrict__ dout) {
  __shared__ float sc32[32];
  int t = threadIdx.x, bx = blockIdx.x;
  if (t == 0) {
    float az = attb[32];
    float m = az;
    for (int i = 0; i < 32; i++) m = fmaxf(m, attb[i]);
    float Z = 160.0f * expf(az - m);
    for (int i = 0; i < 32; i++) Z += expf(attb[i] - m);
    for (int i = 0; i < 32; i++) sc32[i] = expf(attb[i] - m) / Z;
  }
  __syncthreads();
  if (bx == 0 && t < 32) dout[OUT_PS + t] = sc32[t];
  int d = bx * 256 + t;
  int srow0 = (*sel) * 32;
  float acc = 0.f;
#pragma unroll
  for (int i = 0; i < 32; i++) acc += sc32[i] * pmat[(size_t)(srow0 + i) * 1024 + d];
  pattn[d] = acc;
}

// ---------------- K7a: y_in partials: k-split 32, coalesced over 300 outputs
__global__ void k_yin_part(const float* __restrict__ yinp, const float* __restrict__ weighted,
                           const float* __restrict__ pattn, const float* __restrict__ Wy,
                           float* __restrict__ yinP) {
  __shared__ float XLb[74];
  int b = blockIdx.x, t = threadIdx.x;
  int base = b * 74;
  int len = 2348 - base; if (len > 74) len = 74;
  if (t < len) {
    int k = base + t;
    XLb[t] = (k < 300) ? yinp[k] : (k < 1324 ? weighted[k - 300] : pattn[k - 1324]);
  }
  __syncthreads();
  if (t < 300) {
    float acc = 0.f;
    for (int j = 0; j < len; j++) acc += XLb[j] * Wy[(size_t)(base + j) * 300 + t];
    yinP[b * 300 + t] = acc;
  }
}

// ---------------- K7b: gatesP[kq] = y_in@Wih + h0@Whh partials (k-split 8)
__global__ void k_gates_part(const float* __restrict__ yinP, const float* __restrict__ by,
                             const float* __restrict__ hid,
                             const float* __restrict__ Wih, const float* __restrict__ Whh,
                             float* __restrict__ gatesP) {
  __shared__ float YLb[40];
  __shared__ float red[4][64];
  int bx = blockIdx.x, kq = blockIdx.y, t = threadIdx.x;
  int k0i = kq * 38;
  int k1i = k0i + 38; if (k1i > 300) k1i = 300;
  if (t < k1i - k0i) {
    float s = by[k0i + t];
#pragma unroll 8
    for (int b = 0; b < 32; b++) s += yinP[b * 300 + k0i + t];
    YLb[t] = s;
  }
  __syncthreads();
  int ol = t & 63, kc = t >> 6;
  int o = bx * 64 + ol;
  float acc = 0.f;
  for (int k = k0i + kc; k < k1i; k += 4) acc += YLb[k - k0i] * Wih[(size_t)k * 4096 + o];
  int kh0 = kq * 128;
#pragma unroll 4
  for (int k = kh0 + kc; k < kh0 + 128; k += 4) acc += hid[k] * Whh[(size_t)k * 4096 + o];
  red[kc][ol] = acc;
  __syncthreads();
  if (t < 64) {
    int oo = bx * 64 + t;
    gatesP[(size_t)kq * 4096 + oo] = red[0][t] + red[1][t] + red[2][t] + red[3][t];
  }
}

// ---------------- K7c: LSTM pointwise (reduces 8 gate partials) -> h1, c1
__global__ void k_lstm(const float* __restrict__ gatesP, const float* __restrict__ bih,
                       const float* __restrict__ bhh, const float* __restrict__ c0,
                       float* __restrict__ h1ws, float* __restrict__ dout) {
  int t = threadIdx.x;
  for (int q = 0; q < 4; q++) {
    int d = t + q * 256;
    float gi = bih[d] + bhh[d];
    float gf = bih[1024 + d] + bhh[1024 + d];
    float gg = bih[2048 + d] + bhh[2048 + d];
    float go = bih[3072 + d] + bhh[3072 + d];
#pragma unroll
    for (int kq = 0; kq < 8; kq++) {
      const float* g = gatesP + (size_t)kq * 4096;
      gi += g[d]; gf += g[1024 + d]; gg += g[2048 + d]; go += g[3072 + d];
    }
    float c1 = sigmoidf(gf) * c0[d] + sigmoidf(gi) * tanhf(gg);
    float h1 = sigmoidf(go) * tanhf(c1);
    h1ws[d] = h1;
    dout[OUT_H1 + d] = h1;
    dout[OUT_C1 + d] = c1;
  }
}

// ---------------- K8: logits partials = h1 @ Wout, k-split 16, 512-col blocks
__global__ __launch_bounds__(256) void k_out_gemv(const float* __restrict__ h1,
                                                  const float* __restrict__ Wout,
                                                  float* __restrict__ partK) {
  __shared__ float hh[64];
  int ks = blockIdx.x, cb = blockIdx.y, t = threadIdx.x;
  if (t < 64) hh[t] = h1[ks * 64 + t];
  __syncthreads();
  int c0 = cb * 512 + t;
  int c1 = c0 + 256;
  bool v0 = c0 < 50257, v1 = c1 < 50257;
  float a0 = 0.f, a1 = 0.f;
  const float* W = Wout + (size_t)ks * 64 * 50257;
#pragma unroll 8
  for (int k = 0; k < 64; k++) {
    const float* row = W + (size_t)k * 50257;
    float h = hh[k];
    if (v0) a0 += h * row[c0];
    if (v1) a1 += h * row[c1];
  }
  float* dst = partK + (size_t)ks * 50257;
  if (v0) dst[c0] = a0;
  if (v1) dst[c1] = a1;
}

// ---------------- K9a: logits = sum partials + bout ; per-block max & sumexp (197 blocks)
__global__ void k_logits_stats(const float* __restrict__ partK, const float* __restrict__ bout,
                               float* __restrict__ logits, float* __restrict__ bstat) {
  __shared__ float r4[4];
  int bx = blockIdx.x, t = threadIdx.x;
  int c = bx * 256 + t;
  float v = -1e30f;
  if (c < 50257) {
    v = bout[c];
#pragma unroll
    for (int ks = 0; ks < 16; ks++) v += partK[(size_t)ks * 50257 + c];
    logits[c] = v;
  }
  float m = wred_max(v);
  if ((t & 63) == 0) r4[t >> 6] = m;
  __syncthreads();
  m = fmaxf(fmaxf(r4[0], r4[1]), fmaxf(r4[2], r4[3]));
  __syncthreads();
  float z = (c < 50257) ? expf(v - m) : 0.f;
  z = wred_sum(z);
  if ((t & 63) == 0) r4[t >> 6] = z;
  __syncthreads();
  if (t == 0) { bstat[bx] = m; bstat[256 + bx] = r4[0] + r4[1] + r4[2] + r4[3]; }
}

// ---------------- K9c: merge stats (redundant per block) + out = exp(logit - M)/Z
__global__ void k_out_final(const float* __restrict__ bstat, const float* __restrict__ logits,
                            float* __restrict__ dout) {
  __shared__ float r4m[4], r4z[4];
  int bx = blockIdx.x, t = threadIdx.x;
  float mv = (t < 197) ? bstat[t] : -1e30f;
  float m = wred_max(mv);
  if ((t & 63) == 0) r4m[t >> 6] = m;
  __syncthreads();
  m = fmaxf(fmaxf(r4m[0], r4m[1]), fmaxf(r4m[2], r4m[3]));
  __syncthreads();
  float zv = (t < 197) ? bstat[256 + t] * expf(bstat[t] - m) : 0.f;
  float z = wred_sum(zv);
  if ((t & 63) == 0) r4z[t >> 6] = z;
  __syncthreads();
  float Z = r4z[0] + r4z[1] + r4z[2] + r4z[3];
  int c = bx * 256 + t;
  if (c < 50257) dout[c] = expf(logits[c] - m) / Z;
}

extern "C" void kernel_launch(void* const* d_in, const int* in_sizes, int n_in,
                              void* d_out, int out_size, void* d_ws, size_t ws_size,
                              hipStream_t stream) {
  (void)in_sizes; (void)n_in; (void)out_size; (void)ws_size;
  const int*   idx   = (const int*)  d_in[0];
  const float* ex    = (const float*)d_in[1];
  const float* ec    = (const float*)d_in[2];
  const float* pmat  = (const float*)d_in[3];
  const float* hid   = (const float*)d_in[4];
  const float* c0    = (const float*)d_in[5];
  const float* embed = (const float*)d_in[8];
  const float* Wa    = (const float*)d_in[9];
  const float* ba    = (const float*)d_in[10];
  const float* va    = (const float*)d_in[11];
  const float* Wg    = (const float*)d_in[12];
  const float* bg    = (const float*)d_in[13];
  const float* Wchar = (const float*)d_in[14];
  const float* bchar = (const float*)d_in[15];
  const float* Wp    = (const float*)d_in[16];
  const float* bp    = (const float*)d_in[17];
  const float* Wh    = (const float*)d_in[18];
  const float* bh    = (const float*)d_in[19];
  const float* vv    = (const float*)d_in[20];
  const float* Wy    = (const float*)d_in[21];
  const float* by    = (const float*)d_in[22];
  const float* Wih   = (const float*)d_in[23];
  const float* Whh   = (const float*)d_in[24];
  const float* bih   = (const float*)d_in[25];
  const float* bhh   = (const float*)d_in[26];
  const float* Wout  = (const float*)d_in[27];
  const float* bout  = (const float*)d_in[28];
  float* out = (float*)d_out;

  char* ws = (char*)d_ws;
  // Phase-1 zone (dead before k_out_gemv; overlapped by partK/logits):
  unsigned short* WaT = (unsigned short*)(ws + 0);          // 2,097,152
  float* scoresP  = (float*)(ws + 2097152);                 //   393,216 -> 2,490,368
  float* scores   = (float*)(ws + 2490368);                 //    49,152 -> 2,539,520
  float* bmax     = (float*)(ws + 2539520);                 //       256
  float* bz       = (float*)(ws + 2539776);                 //       256
  float* partw    = (float*)(ws + 2540032);                 //   786,432 -> 3,326,464
  float* wxc      = (float*)(ws + 3326464);                 //     8,192
  float* wgP      = (float*)(ws + 3334656);                 //   131,072 -> 3,465,728
  // Phase-2 zone (overlaps phase-1 only):
  float* partK    = (float*)(ws + 0);                       // 3,216,448
  float* logits   = (float*)(ws + 3216640);                 //   201,152 -> 3,417,792
  // Mid/persistent zone, base 3,465,728:
  float* pp       = (float*)(ws + 3465728);                 //   131,072 -> 3,596,800
  float* ppP      = (float*)(ws + 3596800);                 // 2,097,152 -> 5,693,952
  float* pattn    = (float*)(ws + 5693952);                 //     4,096
  float* attb     = (float*)(ws + 5698048);                 //       256
  float* yinP     = (float*)(ws + 5698304);                 //    38,656 -> 5,736,960
  float* gatesP   = (float*)(ws + 5736960);                 //   131,072 -> 5,868,032
  float* hWa      = (float*)(ws + 5868032);                 //     4,096
  float* hWh      = (float*)(ws + 5872128);                 //     4,096
  float* yinp     = (float*)(ws + 5876224);                 //     1,536
  float* nz       = (float*)(ws + 5877760);                 //       256
  float* weighted = (float*)(ws + 5878016);                 //     4,096
  int*   sel      = (int*)  (ws + 5882112);                 //       256
  float* h1       = (float*)(ws + 5882368);                 //     4,096
  float* bstat    = (float*)(ws + 5886464);                 //     2,048  -> 5,888,512 total

  k_prep_bT<<<dim3(16, 16), 256, 0, stream>>>(Wa, WaT);
  k_prep_small<<<39, 512, 0, stream>>>(Wa, ba, Wh, bh, hid, embed, idx, pmat, hWa, hWh, yinp, nz);
  k_scores_gemm<<<dim3(96, 8), 256, 0, stream>>>(ex, ec, WaT, hWa, va, scoresP);
  k_scores_reduce<<<48, 256, 0, stream>>>(scoresP, scores, bmax, bz);
  k_weighted_part<<<dim3(192, 4), 256, 0, stream>>>(ex, ec, scores, bmax, bz, partw);
  k_weighted_combine<<<4, 256, 0, stream>>>(partw, wxc);
  k_weighted_gemv<<<dim3(4, 32), 256, 0, stream>>>(wxc, Wg, wgP);
  k_wgfin_charsel<<<1, 256, 0, stream>>>(wgP, bg, yinp, hid, Wchar, bchar, nz, weighted, sel, out);
  k_pp<<<dim3(4, 16), 256, 0, stream>>>(pmat, Wp, sel, ppP);
  k_pp_fin<<<32, 256, 0, stream>>>(ppP, bp, pp);
  k_att<<<33, 256, 0, stream>>>(pp, hWh, bp, vv, attb);
  k_pattn2<<<4, 256, 0, stream>>>(attb, pmat, sel, pattn, out);
  k_yin_part<<<32, 320, 0, stream>>>(yinp, weighted, pattn, Wy, yinP);
  k_gates_part<<<dim3(64, 8), 256, 0, stream>>>(yinP, by, hid, Wih, Whh, gatesP);
  k_lstm<<<1, 256, 0, stream>>>(gatesP, bih, bhh, c0, h1, out);
  k_out_gemv<<<dim3(16, 100), 256, 0, stream>>>(h1, Wout, partK);
  k_logits_stats<<<197, 256, 0, stream>>>(partK, bout, logits, bstat);
  k_out_final<<<197, 256, 0, stream>>>(bstat, logits, out);
}

// Round 4
// 258.243 us; speedup vs baseline: 2.9677x; 1.0568x over previous
//
#include <hip/hip_runtime.h>
#include <hip/hip_bf16.h>
#include <math.h>

typedef short short8 __attribute__((ext_vector_type(8)));
typedef float f32x4 __attribute__((ext_vector_type(4)));
typedef float f32x4u __attribute__((ext_vector_type(4), aligned(4)));

#define DEV static __device__ __forceinline__

DEV void gl2lds16(const void* g, void* l) {
  __builtin_amdgcn_global_load_lds(
      (const __attribute__((address_space(1))) unsigned int*)g,
      (__attribute__((address_space(3))) unsigned int*)l, 16, 0, 0);
}

DEV float wred_sum(float v) {
#pragma unroll
  for (int o = 1; o < 64; o <<= 1) v += __shfl_xor(v, o, 64);
  return v;
}
DEV float wred_max(float v) {
#pragma unroll
  for (int o = 1; o < 64; o <<= 1) v = fmaxf(v, __shfl_xor(v, o, 64));
  return v;
}
DEV float sigmoidf(float x) { return 1.0f / (1.0f + expf(-x)); }

DEV unsigned short f2bf(float x) {
  unsigned u = __float_as_uint(x);
  unsigned rr = (u + 0x7fffu + ((u >> 16) & 1u)) >> 16;
  return (unsigned short)rr;
}

DEV short8 cvt8(float4 f0, float4 f1) {
  union { short8 s; unsigned u[4]; } r;
  asm("v_cvt_pk_bf16_f32 %0, %1, %2" : "=v"(r.u[0]) : "v"(f0.x), "v"(f0.y));
  asm("v_cvt_pk_bf16_f32 %0, %1, %2" : "=v"(r.u[1]) : "v"(f0.z), "v"(f0.w));
  asm("v_cvt_pk_bf16_f32 %0, %1, %2" : "=v"(r.u[2]) : "v"(f1.x), "v"(f1.y));
  asm("v_cvt_pk_bf16_f32 %0, %1, %2" : "=v"(r.u[3]) : "v"(f1.z), "v"(f1.w));
  return r.s;
}

// output layout (floats): out[50257] | h1[1024] | c1[1024] | weighted[1024] | psel[32]
#define OUT_H1 50257
#define OUT_C1 51281
#define OUT_W  52305
#define OUT_PS 53329
#define PKS 50260  // padded partK row stride (mult of 4)

// ---------------- P-1: convert ex||ec (12288x1024 fp32) -> encb bf16, flat
__global__ __launch_bounds__(256) void k_enc_bf16(const float* __restrict__ ex,
                                                  const float* __restrict__ ec,
                                                  unsigned short* __restrict__ encb) {
  size_t i = ((size_t)blockIdx.x * 256 + threadIdx.x) * 8;  // 12,582,912 total
  const float* src = (i < 8388608) ? (ex + i) : (ec + (i - 8388608));
  float4 f0 = *(const float4*)src;
  float4 f1 = *(const float4*)(src + 4);
  *(short8*)&encb[i] = cvt8(f0, f1);
}

// ---------------- P0: transpose+convert Wa_bot (rows 1024..2047) -> WaT[n][k] bf16
__global__ void k_prep_bT(const float* __restrict__ Wa, unsigned short* __restrict__ WaT) {
  __shared__ float tile[64][65];
  int bi = blockIdx.x, bj = blockIdx.y, t = threadIdx.x;
  int c = t & 63, rq = t >> 6;
#pragma unroll
  for (int rr = 0; rr < 16; rr++) {
    int kl = rr * 4 + rq;
    tile[kl][c] = Wa[(size_t)(1024 + bi * 64 + kl) * 1024 + bj * 64 + c];
  }
  __syncthreads();
#pragma unroll
  for (int rr = 0; rr < 16; rr++) {
    int nl = rr * 4 + rq;
    WaT[(size_t)(bj * 64 + nl) * 1024 + bi * 64 + c] = f2bf(tile[c][nl]);
  }
}

// ---------------- K1: hWa = h0@Wa_top + ba ; hWh = h0@Wh + bh ; embed gather ; nz sums
__global__ void k_prep_small(const float* __restrict__ Wa, const float* __restrict__ ba,
                             const float* __restrict__ Wh, const float* __restrict__ bh,
                             const float* __restrict__ hid, const float* __restrict__ embed,
                             const int* __restrict__ idx, const float* __restrict__ pmat,
                             float* __restrict__ hWa, float* __restrict__ hWh,
                             float* __restrict__ yinp, float* __restrict__ nz) {
  __shared__ float red[8][64];
  __shared__ float r2[8];
  int bx = blockIdx.x, t = threadIdx.x;
  if (bx < 32) {
    int ol = t & 63, kc = t >> 6;
    int o = bx * 64 + ol;
    const float* W = (o < 1024) ? Wa : Wh;
    int col = (o < 1024) ? o : (o - 1024);
    float acc = 0.f;
#pragma unroll 4
    for (int k = kc * 128; k < kc * 128 + 128; k++) acc += hid[k] * W[(size_t)k * 1024 + col];
    red[kc][ol] = acc;
    __syncthreads();
    if (t < 64) {
      int oo = bx * 64 + t;
      float s = 0.f;
#pragma unroll
      for (int q = 0; q < 8; q++) s += red[q][t];
      if (oo < 1024) hWa[oo] = s + ba[oo];
      else hWh[oo - 1024] = s + bh[oo - 1024];
    }
  } else if (bx == 32) {
    int id = idx[0];
    for (int k = t; k < 300; k += 512) yinp[k] = embed[(size_t)id * 300 + k];
  } else {
    int j = bx - 33;
    float a = 0.f;
    for (int k = t; k < 32768; k += 512) a += pmat[(size_t)j * 32768 + k];
    a = wred_sum(a);
    if ((t & 63) == 0) r2[t >> 6] = a;
    __syncthreads();
    if (t == 0) {
      float s = 0.f;
#pragma unroll
      for (int q = 0; q < 8; q++) s += r2[q];
      nz[j] = s;
    }
  }
}

// ---------------- K2: scores GEMM, all-bf16, BK=64, XOR-swizzled LDS (slot ^= row&7)
__global__ __launch_bounds__(256) void k_scores_gemm(
    const unsigned short* __restrict__ encb, const unsigned short* __restrict__ WaT,
    const float* __restrict__ hWa, const float* __restrict__ va,
    float* __restrict__ scoresP) {
  __shared__ __align__(16) unsigned short As[128 * 64];  // 16 KB, swizzled
  __shared__ __align__(16) unsigned short Bs[128 * 64];  // 16 KB, swizzled
  __shared__ float red[2][128];
  int mtile = blockIdx.x, ntile = blockIdx.y;
  int t = threadIdx.x, lane = t & 63, wid = t >> 6;
  int wr = wid >> 1, wc = wid & 1;
  int l15 = lane & 15, lg = lane >> 4;
  int r0 = mtile * 128;

  f32x4 acc[4][4];
#pragma unroll
  for (int m = 0; m < 4; m++)
#pragma unroll
    for (int n = 0; n < 4; n++) acc[m][n] = (f32x4){0.f, 0.f, 0.f, 0.f};

  for (int kt = 0; kt < 1024; kt += 64) {
    // stage A: 128x64 bf16 = 1024 16B-chunks; chunk c: row=c>>3, slot=c&7.
    // LDS dest is linear; global source slot is pre-swizzled (slot ^ row&7).
#pragma unroll
    for (int p = 0; p < 4; p++) {
      int c = p * 256 + t;
      int row = c >> 3, slot = c & 7;
      const unsigned short* g =
          encb + (size_t)(r0 + row) * 1024 + kt + ((slot ^ (row & 7)) * 8);
      gl2lds16(g, &As[c * 8]);
    }
#pragma unroll
    for (int p = 0; p < 4; p++) {
      int c = p * 256 + t;
      int row = c >> 3, slot = c & 7;
      const unsigned short* g =
          WaT + (size_t)(ntile * 128 + row) * 1024 + kt + ((slot ^ (row & 7)) * 8);
      gl2lds16(g, &Bs[c * 8]);
    }
    __syncthreads();
#pragma unroll
    for (int ks = 0; ks < 2; ks++) {
      short8 a[4], b[4];
      int q = ks * 4 + lg;
#pragma unroll
      for (int m = 0; m < 4; m++) {
        int row = wr * 64 + m * 16 + l15;
        a[m] = *(const short8*)&As[row * 64 + ((q ^ (row & 7)) * 8)];
      }
#pragma unroll
      for (int n = 0; n < 4; n++) {
        int nr = wc * 64 + n * 16 + l15;
        b[n] = *(const short8*)&Bs[nr * 64 + ((q ^ (nr & 7)) * 8)];
      }
#pragma unroll
      for (int m = 0; m < 4; m++)
#pragma unroll
        for (int n = 0; n < 4; n++)
          acc[m][n] = __builtin_amdgcn_mfma_f32_16x16x32_bf16(a[m], b[n], acc[m][n], 0, 0, 0);
    }
    __syncthreads();
  }

  float vva[4], hba[4];
#pragma unroll
  for (int n = 0; n < 4; n++) {
    int col = ntile * 128 + wc * 64 + n * 16 + l15;
    vva[n] = va[col];
    hba[n] = hWa[col];
  }
#pragma unroll
  for (int m = 0; m < 4; m++) {
#pragma unroll
    for (int j = 0; j < 4; j++) {
      float p = 0.f;
#pragma unroll
      for (int n = 0; n < 4; n++) p += vva[n] * tanhf(acc[m][n][j] + hba[n]);
#pragma unroll
      for (int o = 1; o < 16; o <<= 1) p += __shfl_xor(p, o, 64);
      if (l15 == 0) red[wc][wr * 64 + m * 16 + lg * 4 + j] = p;
    }
  }
  __syncthreads();
  if (t < 128) scoresP[(size_t)ntile * 12288 + r0 + t] = red[0][t] + red[1][t];
}

// ---------------- K2b: scores[r] = sum over 8 ntiles ; fused per-block softmax stats
__global__ void k_scores_reduce(const float* __restrict__ scoresP, float* __restrict__ scores,
                                float* __restrict__ bmax, float* __restrict__ bz) {
  __shared__ float r4[4];
  int bx = blockIdx.x, t = threadIdx.x;
  int r = bx * 256 + t;
  float s = 0.f;
#pragma unroll
  for (int nt = 0; nt < 8; nt++) s += scoresP[(size_t)nt * 12288 + r];
  scores[r] = s;
  float m = wred_max(s);
  if ((t & 63) == 0) r4[t >> 6] = m;
  __syncthreads();
  m = fmaxf(fmaxf(r4[0], r4[1]), fmaxf(r4[2], r4[3]));
  __syncthreads();
  float z = expf(s - m);
  z = wred_sum(z);
  if ((t & 63) == 0) r4[t >> 6] = z;
  __syncthreads();
  if (t == 0) { bmax[bx] = m; bz[bx] = r4[0] + r4[1] + r4[2] + r4[3]; }
}

// ---------------- K3: weighted-sum partials from bf16 encb; 64-row x 512-col tiles
__global__ void k_weighted_part(const unsigned short* __restrict__ encb,
                                const float* __restrict__ scores, const float* __restrict__ bmax,
                                const float* __restrict__ bz, float* __restrict__ partw) {
  __shared__ float wrow[64];
  int b = blockIdx.x, colq = blockIdx.y, t = threadIdx.x;
  int seg = (b >= 128) ? 1 : 0;
  int sbase = seg ? 8192 : 0;
  int rb = seg ? (b - 128) * 64 : b * 64;  // segment-local
  if (t < 64) {
    int b0 = seg ? 32 : 0, cnt = seg ? 16 : 32;
    float mv = (t < cnt) ? bmax[b0 + t] : -1e30f;
    float m = wred_max(mv);
    float zv = (t < cnt) ? bz[b0 + t] * expf(bmax[b0 + t] - m) : 0.f;
    float z = wred_sum(zv);
    wrow[t] = expf(scores[sbase + rb + t] - m) / z;
  }
  __syncthreads();
  int c2 = colq * 512 + 2 * t;
  float a0 = 0.f, a1 = 0.f;
  size_t rowbase = (size_t)b * 64 * 1024;  // global row = b*64 (flat encb works for both segs)
#pragma unroll 8
  for (int r = 0; r < 64; r++) {
    unsigned u = *(const unsigned*)&encb[rowbase + (size_t)r * 1024 + c2];
    float w = wrow[r];
    a0 += w * __uint_as_float(u << 16);
    a1 += w * __uint_as_float(u & 0xffff0000u);
  }
  float2 o; o.x = a0; o.y = a1;
  *(float2*)&partw[(size_t)b * 1024 + c2] = o;
}

// ---------------- K3c: combine -> wxc[0:1024]=weighted_x, [1024:2048]=weighted_c
__global__ void k_weighted_combine(const float* __restrict__ partw, float* __restrict__ wxc) {
  int d = blockIdx.x * 256 + threadIdx.x;
  float sx = 0.f, sc = 0.f;
#pragma unroll 8
  for (int b = 0; b < 128; b++) sx += partw[(size_t)b * 1024 + d];
#pragma unroll 8
  for (int b = 128; b < 192; b++) sc += partw[(size_t)b * 1024 + d];
  wxc[d] = sx; wxc[1024 + d] = sc;
}

// ---------------- K4: weighted partials = wxc @ Wg, k-split 32
__global__ void k_weighted_gemv(const float* __restrict__ wxc, const float* __restrict__ Wg,
                                float* __restrict__ wgP) {
  int o = blockIdx.x * 256 + threadIdx.x;
  int kb = blockIdx.y * 64;
  float acc = 0.f;
#pragma unroll 8
  for (int k = kb; k < kb + 64; k++) acc += wxc[k] * Wg[(size_t)k * 1024 + o];
  wgP[(size_t)blockIdx.y * 1024 + o] = acc;
}

// ---------------- K4b+K5: weighted = sum partials + bg ; char gate argmax -> sel
__global__ void k_wgfin_charsel(const float* __restrict__ wgP, const float* __restrict__ bg,
                                const float* __restrict__ yinp, const float* __restrict__ hid,
                                const float* __restrict__ Wchar, const float* __restrict__ bchar,
                                const float* __restrict__ nz, float* __restrict__ weighted,
                                int* __restrict__ sel, float* __restrict__ dout) {
  __shared__ float WL[1024];
  __shared__ float red[4][6];
  int t = threadIdx.x;
  for (int q = 0; q < 4; q++) {
    int d = t + q * 256;
    float s = bg[d];
#pragma unroll 8
    for (int b = 0; b < 32; b++) s += wgP[(size_t)b * 1024 + d];
    WL[d] = s;
    weighted[d] = s;
    dout[OUT_W + d] = s;
  }
  __syncthreads();
  float p[6] = {0.f, 0.f, 0.f, 0.f, 0.f, 0.f};
  for (int k = t; k < 2348; k += 256) {
    float xv = (k < 300) ? yinp[k] : (k < 1324 ? hid[k - 300] : WL[k - 1324]);
#pragma unroll
    for (int ch = 0; ch < 6; ch++) p[ch] += xv * Wchar[k * 6 + ch];
  }
#pragma unroll
  for (int ch = 0; ch < 6; ch++) {
    float v = wred_sum(p[ch]);
    if ((t & 63) == 0) red[t >> 6][ch] = v;
  }
  __syncthreads();
  if (t == 0) {
    float best = -1e30f; int si = 0;
    for (int ch = 0; ch < 6; ch++) {
      float lgt = red[0][ch] + red[1][ch] + red[2][ch] + red[3][ch] + bchar[ch];
      if (nz[ch] != 0.0f && lgt > best) { best = lgt; si = ch; }
    }
    *sel = si;
  }
}

// ---------------- K6a: ppP[kq][i][o] partials; Wp element read once for all 32 rows
__global__ void k_pp(const float* __restrict__ pmat, const float* __restrict__ Wp,
                     const int* __restrict__ sel, float* __restrict__ ppP) {
  __shared__ float sr[32][64];
  int oq = blockIdx.x, kq = blockIdx.y, t = threadIdx.x;
  int row0 = (*sel) * 32;
  int k0 = kq * 64;
#pragma unroll
  for (int j = 0; j < 8; j++) {
    int idx = t + j * 256;
    int i = idx >> 6, kk = idx & 63;
    sr[i][kk] = pmat[(size_t)(row0 + i) * 1024 + k0 + kk];
  }
  __syncthreads();
  int o = oq * 256 + t;
  float acc[32];
#pragma unroll
  for (int i = 0; i < 32; i++) acc[i] = 0.f;
  for (int k = 0; k < 64; k++) {
    float w = Wp[(size_t)(k0 + k) * 1024 + o];
#pragma unroll
    for (int i = 0; i < 32; i++) acc[i] += sr[i][k] * w;
  }
#pragma unroll
  for (int i = 0; i < 32; i++) ppP[(size_t)kq * 32768 + i * 1024 + o] = acc[i];
}

// ---------------- K6b (fused pp_fin + att): pp[i] = sum ppP + bp ; att[i] = vv . tanh(hWh+pp)
__global__ void k_ppfin_att(const float* __restrict__ ppP, const float* __restrict__ bp,
                            const float* __restrict__ hWh, const float* __restrict__ vv,
                            float* __restrict__ pp, float* __restrict__ attb) {
  __shared__ float r4[4];
  int i = blockIdx.x, t = threadIdx.x;
  float pt = 0.f;
  if (i < 32) {
    for (int q = 0; q < 4; q++) {
      int d = t + q * 256;
      float s = bp[d];
#pragma unroll
      for (int kq = 0; kq < 16; kq++) s += ppP[(size_t)kq * 32768 + i * 1024 + d];
      pp[i * 1024 + d] = s;
      pt += vv[d] * tanhf(hWh[d] + s);
    }
  } else {
    for (int q = 0; q < 4; q++) {
      int d = t + q * 256;
      pt += vv[d] * tanhf(hWh[d] + bp[d]);
    }
  }
  pt = wred_sum(pt);
  if ((t & 63) == 0) r4[t >> 6] = pt;
  __syncthreads();
  if (t == 0) attb[i] = r4[0] + r4[1] + r4[2] + r4[3];
}

// ---------------- K6c: softmax over 192 (160 zero-slots share att_zero) -> psel + p_attn
__global__ void k_pattn2(const float* __restrict__ attb, const float* __restrict__ pmat,
                         const int* __restrict__ sel, float* __restrict__ pattn,
                         float* __restrict__ dout) {
  __shared__ float sc32[32];
  int t = threadIdx.x, bx = blockIdx.x;
  if (t == 0) {
    float az = attb[32];
    float m = az;
    for (int i = 0; i < 32; i++) m = fmaxf(m, attb[i]);
    float Z = 160.0f * expf(az - m);
    for (int i = 0; i < 32; i++) Z += expf(attb[i] - m);
    for (int i = 0; i < 32; i++) sc32[i] = expf(attb[i] - m) / Z;
  }
  __syncthreads();
  if (bx == 0 && t < 32) dout[OUT_PS + t] = sc32[t];
  int d = bx * 256 + t;
  int srow0 = (*sel) * 32;
  float acc = 0.f;
#pragma unroll
  for (int i = 0; i < 32; i++) acc += sc32[i] * pmat[(size_t)(srow0 + i) * 1024 + d];
  pattn[d] = acc;
}

// ---------------- K7a: y_in partials: k-split 32, coalesced over 300 outputs
__global__ void k_yin_part(const float* __restrict__ yinp, const float* __restrict__ weighted,
                           const float* __restrict__ pattn, const float* __restrict__ Wy,
                           float* __restrict__ yinP) {
  __shared__ float XLb[74];
  int b = blockIdx.x, t = threadIdx.x;
  int base = b * 74;
  int len = 2348 - base; if (len > 74) len = 74;
  if (t < len) {
    int k = base + t;
    XLb[t] = (k < 300) ? yinp[k] : (k < 1324 ? weighted[k - 300] : pattn[k - 1324]);
  }
  __syncthreads();
  if (t < 300) {
    float acc = 0.f;
    for (int j = 0; j < len; j++) acc += XLb[j] * Wy[(size_t)(base + j) * 300 + t];
    yinP[b * 300 + t] = acc;
  }
}

// ---------------- K7b: gatesP[kq] = y_in@Wih + h0@Whh partials (k-split 8)
__global__ void k_gates_part(const float* __restrict__ yinP, const float* __restrict__ by,
                             const float* __restrict__ hid,
                             const float* __restrict__ Wih, const float* __restrict__ Whh,
                             float* __restrict__ gatesP) {
  __shared__ float YLb[40];
  __shared__ float red[4][64];
  int bx = blockIdx.x, kq = blockIdx.y, t = threadIdx.x;
  int k0i = kq * 38;
  int k1i = k0i + 38; if (k1i > 300) k1i = 300;
  if (t < k1i - k0i) {
    float s = by[k0i + t];
#pragma unroll 8
    for (int b = 0; b < 32; b++) s += yinP[b * 300 + k0i + t];
    YLb[t] = s;
  }
  __syncthreads();
  int ol = t & 63, kc = t >> 6;
  int o = bx * 64 + ol;
  float acc = 0.f;
  for (int k = k0i + kc; k < k1i; k += 4) acc += YLb[k - k0i] * Wih[(size_t)k * 4096 + o];
  int kh0 = kq * 128;
#pragma unroll 4
  for (int k = kh0 + kc; k < kh0 + 128; k += 4) acc += hid[k] * Whh[(size_t)k * 4096 + o];
  red[kc][ol] = acc;
  __syncthreads();
  if (t < 64) {
    int oo = bx * 64 + t;
    gatesP[(size_t)kq * 4096 + oo] = red[0][t] + red[1][t] + red[2][t] + red[3][t];
  }
}

// ---------------- K7c: LSTM pointwise (reduces 8 gate partials) -> h1, c1
__global__ void k_lstm(const float* __restrict__ gatesP, const float* __restrict__ bih,
                       const float* __restrict__ bhh, const float* __restrict__ c0,
                       float* __restrict__ h1ws, float* __restrict__ dout) {
  int t = threadIdx.x;
  for (int q = 0; q < 4; q++) {
    int d = t + q * 256;
    float gi = bih[d] + bhh[d];
    float gf = bih[1024 + d] + bhh[1024 + d];
    float gg = bih[2048 + d] + bhh[2048 + d];
    float go = bih[3072 + d] + bhh[3072 + d];
#pragma unroll
    for (int kq = 0; kq < 8; kq++) {
      const float* g = gatesP + (size_t)kq * 4096;
      gi += g[d]; gf += g[1024 + d]; gg += g[2048 + d]; go += g[3072 + d];
    }
    float c1 = sigmoidf(gf) * c0[d] + sigmoidf(gi) * tanhf(gg);
    float h1 = sigmoidf(go) * tanhf(c1);
    h1ws[d] = h1;
    dout[OUT_H1 + d] = h1;
    dout[OUT_C1 + d] = c1;
  }
}

// ---------------- K8: logits partials = h1 @ Wout, k-split 16, float4 cols
__global__ __launch_bounds__(256) void k_out_gemv(const float* __restrict__ h1,
                                                  const float* __restrict__ Wout,
                                                  float* __restrict__ partK) {
  __shared__ float hh[64];
  int ks = blockIdx.x, cb = blockIdx.y, t = threadIdx.x;
  if (t < 64) hh[t] = h1[ks * 64 + t];
  __syncthreads();
  const float* W = Wout + (size_t)ks * 64 * 50257;
  int c4 = cb * 1024 + t * 4;
  if (c4 + 4 <= 50257) {
    f32x4 a = (f32x4){0.f, 0.f, 0.f, 0.f};
#pragma unroll 4
    for (int k = 0; k < 64; k++) {
      f32x4u w = *(const f32x4u*)&W[(size_t)k * 50257 + c4];
      float h = hh[k];
      a[0] += h * w[0]; a[1] += h * w[1]; a[2] += h * w[2]; a[3] += h * w[3];
    }
    *(f32x4*)&partK[(size_t)ks * PKS + c4] = a;
  } else if (c4 < 50257) {
    for (int c = c4; c < 50257; c++) {
      float a = 0.f;
#pragma unroll 8
      for (int k = 0; k < 64; k++) a += hh[k] * W[(size_t)k * 50257 + c];
      partK[(size_t)ks * PKS + c] = a;
    }
  }
}

// ---------------- K9a: logits = sum partials + bout ; per-block max & sumexp (197 blocks)
__global__ void k_logits_stats(const float* __restrict__ partK, const float* __restrict__ bout,
                               float* __restrict__ logits, float* __restrict__ bstat) {
  __shared__ float r4[4];
  int bx = blockIdx.x, t = threadIdx.x;
  int c = bx * 256 + t;
  float v = -1e30f;
  if (c < 50257) {
    v = bout[c];
#pragma unroll
    for (int ks = 0; ks < 16; ks++) v += partK[(size_t)ks * PKS + c];
    logits[c] = v;
  }
  float m = wred_max(v);
  if ((t & 63) == 0) r4[t >> 6] = m;
  __syncthreads();
  m = fmaxf(fmaxf(r4[0], r4[1]), fmaxf(r4[2], r4[3]));
  __syncthreads();
  float z = (c < 50257) ? expf(v - m) : 0.f;
  z = wred_sum(z);
  if ((t & 63) == 0) r4[t >> 6] = z;
  __syncthreads();
  if (t == 0) { bstat[bx] = m; bstat[256 + bx] = r4[0] + r4[1] + r4[2] + r4[3]; }
}

// ---------------- K9c: merge stats (redundant per block) + out = exp(logit - M)/Z
__global__ void k_out_final(const float* __restrict__ bstat, const float* __restrict__ logits,
                            float* __restrict__ dout) {
  __shared__ float r4m[4], r4z[4];
  int bx = blockIdx.x, t = threadIdx.x;
  float mv = (t < 197) ? bstat[t] : -1e30f;
  float m = wred_max(mv);
  if ((t & 63) == 0) r4m[t >> 6] = m;
  __syncthreads();
  m = fmaxf(fmaxf(r4m[0], r4m[1]), fmaxf(r4m[2], r4m[3]));
  __syncthreads();
  float zv = (t < 197) ? bstat[256 + t] * expf(bstat[t] - m) : 0.f;
  float z = wred_sum(zv);
  if ((t & 63) == 0) r4z[t >> 6] = z;
  __syncthreads();
  float Z = r4z[0] + r4z[1] + r4z[2] + r4z[3];
  int c = bx * 256 + t;
  if (c < 50257) dout[c] = expf(logits[c] - m) / Z;
}

extern "C" void kernel_launch(void* const* d_in, const int* in_sizes, int n_in,
                              void* d_out, int out_size, void* d_ws, size_t ws_size,
                              hipStream_t stream) {
  (void)in_sizes; (void)n_in; (void)out_size; (void)ws_size;
  const int*   idx   = (const int*)  d_in[0];
  const float* ex    = (const float*)d_in[1];
  const float* ec    = (const float*)d_in[2];
  const float* pmat  = (const float*)d_in[3];
  const float* hid   = (const float*)d_in[4];
  const float* c0    = (const float*)d_in[5];
  const float* embed = (const float*)d_in[8];
  const float* Wa    = (const float*)d_in[9];
  const float* ba    = (const float*)d_in[10];
  const float* va    = (const float*)d_in[11];
  const float* Wg    = (const float*)d_in[12];
  const float* bg    = (const float*)d_in[13];
  const float* Wchar = (const float*)d_in[14];
  const float* bchar = (const float*)d_in[15];
  const float* Wp    = (const float*)d_in[16];
  const float* bp    = (const float*)d_in[17];
  const float* Wh    = (const float*)d_in[18];
  const float* bh    = (const float*)d_in[19];
  const float* vv    = (const float*)d_in[20];
  const float* Wy    = (const float*)d_in[21];
  const float* by    = (const float*)d_in[22];
  const float* Wih   = (const float*)d_in[23];
  const float* Whh   = (const float*)d_in[24];
  const float* bih   = (const float*)d_in[25];
  const float* bhh   = (const float*)d_in[26];
  const float* Wout  = (const float*)d_in[27];
  const float* bout  = (const float*)d_in[28];
  float* out = (float*)d_out;

  char* ws = (char*)d_ws;
  // Phase-1 zone (dead before k_out_gemv):
  unsigned short* encb = (unsigned short*)(ws + 0);         // 25,165,824
  unsigned short* WaT  = (unsigned short*)(ws + 25165824);  //  2,097,152 -> 27,262,976
  float* scoresP  = (float*)(ws + 27262976);                //    393,216 -> 27,656,192
  float* scores   = (float*)(ws + 27656192);                //     49,152 -> 27,705,344
  float* bmax     = (float*)(ws + 27705344);                //        256
  float* bz       = (float*)(ws + 27705600);                //        256
  float* partw    = (float*)(ws + 27705856);                //    786,432 -> 28,492,288
  float* wxc      = (float*)(ws + 28492288);                //      8,192
  float* wgP      = (float*)(ws + 28500480);                //    131,072 -> 28,631,552
  // Phase-2 zone (overlaps phase-1 only):
  float* partK    = (float*)(ws + 0);                       //  3,216,640 (16 x 50260 x 4)
  float* logits   = (float*)(ws + 3216640);                 //    201,152 -> 3,417,792
  // Persistent zone, base 28,631,552:
  float* pp       = (float*)(ws + 28631552);                //    131,072 -> 28,762,624
  float* ppP      = (float*)(ws + 28762624);                //  2,097,152 -> 30,859,776
  float* pattn    = (float*)(ws + 30859776);                //      4,096
  float* attb     = (float*)(ws + 30863872);                //        256
  float* yinP     = (float*)(ws + 30864128);                //     38,656 -> 30,902,784
  float* gatesP   = (float*)(ws + 30902784);                //    131,072 -> 31,033,856
  float* hWa      = (float*)(ws + 31033856);                //      4,096
  float* hWh      = (float*)(ws + 31037952);                //      4,096
  float* yinp     = (float*)(ws + 31042048);                //      1,536
  float* nz       = (float*)(ws + 31043584);                //        256
  float* weighted = (float*)(ws + 31043840);                //      4,096
  int*   sel      = (int*)  (ws + 31047936);                //        256
  float* h1       = (float*)(ws + 31048192);                //      4,096
  float* bstat    = (float*)(ws + 31052288);                //      2,048 -> 31,054,336 total

  k_enc_bf16<<<6144, 256, 0, stream>>>(ex, ec, encb);
  k_prep_bT<<<dim3(16, 16), 256, 0, stream>>>(Wa, WaT);
  k_prep_small<<<39, 512, 0, stream>>>(Wa, ba, Wh, bh, hid, embed, idx, pmat, hWa, hWh, yinp, nz);
  k_scores_gemm<<<dim3(96, 8), 256, 0, stream>>>(encb, WaT, hWa, va, scoresP);
  k_scores_reduce<<<48, 256, 0, stream>>>(scoresP, scores, bmax, bz);
  k_weighted_part<<<dim3(192, 2), 256, 0, stream>>>(encb, scores, bmax, bz, partw);
  k_weighted_combine<<<4, 256, 0, stream>>>(partw, wxc);
  k_weighted_gemv<<<dim3(4, 32), 256, 0, stream>>>(wxc, Wg, wgP);
  k_wgfin_charsel<<<1, 256, 0, stream>>>(wgP, bg, yinp, hid, Wchar, bchar, nz, weighted, sel, out);
  k_pp<<<dim3(4, 16), 256, 0, stream>>>(pmat, Wp, sel, ppP);
  k_ppfin_att<<<33, 256, 0, stream>>>(ppP, bp, hWh, vv, pp, attb);
  k_pattn2<<<4, 256, 0, stream>>>(attb, pmat, sel, pattn, out);
  k_yin_part<<<32, 320, 0, stream>>>(yinp, weighted, pattn, Wy, yinP);
  k_gates_part<<<dim3(64, 8), 256, 0, stream>>>(yinP, by, hid, Wih, Whh, gatesP);
  k_lstm<<<1, 256, 0, stream>>>(gatesP, bih, bhh, c0, h1, out);
  k_out_gemv<<<dim3(16, 50), 256, 0, stream>>>(h1, Wout, partK);
  k_logits_stats<<<197, 256, 0, stream>>>(partK, bout, logits, bstat);
  k_out_final<<<197, 256, 0, stream>>>(bstat, logits, out);
}